// Round 1
// baseline (2945.890 us; speedup 1.0000x reference)
//
#include <hip/hip_runtime.h>
#include <hip/hip_bf16.h>

using bf16 = __hip_bfloat16;
using bf16x8 = __attribute__((ext_vector_type(8))) short;   // 8 bf16 = 4 VGPRs
using f32x4  = __attribute__((ext_vector_type(4))) float;
using u32x4  = __attribute__((ext_vector_type(4))) unsigned int;
typedef unsigned long long u64;

#define S_LEN 256
#define NBATCH 32
#define HDIM 1024
#define NBLK 256
#define SENT 0x7F7F7F7Fu   // packed bf16 pair 0x7F7F = 3.3e38: impossible for |h|<1
#define SENT64 0x7F7F7F7F7F7F7F7Full

__device__ __forceinline__ float fast_sig(float x) {
    return __builtin_amdgcn_rcpf(1.f + __expf(-x));
}
__device__ __forceinline__ float fast_tanh(float x) {
    return 1.f - 2.f * __builtin_amdgcn_rcpf(1.f + __expf(2.f * x));
}
// staleness per 32-bit word: any torn/unpublished word shows as SENT
__device__ __forceinline__ bool stale4(u32x4 v) {
    return (v.x == SENT) | (v.y == SENT) | (v.z == SENT) | (v.w == SENT);
}

// ---------------------------------------------------------------------------
// Convert x (f32, [n][s][d]) -> xT (bf16, [s][n][d]).
// ---------------------------------------------------------------------------
__global__ __launch_bounds__(256) void convert_x(const float* __restrict__ x,
                                                 bf16* __restrict__ xT) {
    const int p = blockIdx.x;          // p = n*256 + s
    const int n = p >> 8;
    const int s = p & 255;
    const float* src = x + (size_t)p * 1024;
    bf16* dst = xT + (size_t)(s * NBATCH + n) * 1024;
#pragma unroll
    for (int j = 0; j < 4; j++) {
        const int d = threadIdx.x + j * 256;
        dst[d] = (bf16)src[d];
    }
}

// ---------------------------------------------------------------------------
// Convert + transpose: 8 matrices of 1024x1024, f32 in, bf16 out,
// out[g][c][r] = in[g][r][c]
// ---------------------------------------------------------------------------
__global__ __launch_bounds__(256) void convert_transpose_1024(const float* __restrict__ in,
                                                              bf16* __restrict__ out) {
    __shared__ float t[32][33];
    const int g  = blockIdx.z;
    const float* A = in  + (size_t)g * 1024 * 1024;
    bf16*        B = out + (size_t)g * 1024 * 1024;
    const int c0 = blockIdx.x * 32;
    const int r0 = blockIdx.y * 32;
    const int tx = threadIdx.x, ty = threadIdx.y;   // (32, 8)
#pragma unroll
    for (int j = 0; j < 32; j += 8)
        t[ty + j][tx] = A[(size_t)(r0 + ty + j) * 1024 + c0 + tx];
    __syncthreads();
#pragma unroll
    for (int j = 0; j < 32; j += 8)
        B[(size_t)(c0 + ty + j) * 1024 + r0 + tx] = (bf16)t[tx][ty + j];
}

// ---------------------------------------------------------------------------
// Persistent BiLSTM — flag-free, self-synchronizing via data sentinels.
// This round: dwordx4 sc1 h-loads (half the fabric requests), s_sleep poll
// backoff, raw s_barrier (no vmcnt(0) drains on the critical path), hoisted
// mask load, nontemporal out stores.
// ---------------------------------------------------------------------------
__global__ __launch_bounds__(1024) void lstm_persistent(
        const bf16* __restrict__ xT,
        const bf16* __restrict__ wihT,
        const bf16* __restrict__ whhT,
        const float* __restrict__ mask,
        const float* __restrict__ bias,
        unsigned* __restrict__ hbuf,    // [4 slot][2 dir][32 n][512] u32 (bf16 pairs)
        float* __restrict__ out) {
    __shared__ float part[16 * 1024];   // 64 KB: slab w = [32 rows][32 cols] swizzled

    const int bi   = blockIdx.x;
    const int dir  = bi >> 7;
    const int col0 = (bi & 127) << 3;
    const int tid  = threadIdx.x;
    const int w    = tid >> 6;
    const int lane = tid & 63;
    const int r    = lane & 15;
    const int q    = lane >> 4;
    const int kbase = w * 64 + q * 8;   // this wave's K-slice origin (+quad)

    // ---- pin weights: B-frags for both matrices, both gate-pairs ----
    bf16x8 bx[2][2], bh[2][2];
#pragma unroll
    for (int gp = 0; gp < 2; gp++) {
        const int gate = gp * 2 + (r >> 3);
        const size_t rowoff = ((size_t)((dir * 4 + gate) * 1024 + col0 + (r & 7))) * 1024 + kbase;
#pragma unroll
        for (int it = 0; it < 2; it++) {
            bx[gp][it] = *(const bf16x8*)(wihT + rowoff + it * 32);
            bh[gp][it] = *(const bf16x8*)(whhT + rowoff + it * 32);
        }
    }

    // ---- update-thread state (tid<256 owns (n = tid>>3, c = tid&7)) ----
    const int un = tid >> 3;
    const int uc = tid & 7;
    float creg = 0.f, hreg = 0.f;
    float b0 = 0.f, b1 = 0.f, b2 = 0.f, b3 = 0.f;
    if (tid < 256) {
        const int gb = (dir * 4) * 1024 + col0 + uc;
        b0 = bias[gb];
        b1 = bias[gb + 1024];
        b2 = bias[gb + 2048];
        b3 = bias[gb + 3072];
    }
    const int rx = (un & 7) * 4;        // update-read swizzle

    const f32x4 vzero = {0.f, 0.f, 0.f, 0.f};
    f32x4 accA[2][2], accB[2][2];
#pragma unroll
    for (int mh = 0; mh < 2; mh++) { accB[mh][0] = vzero; accB[mh][1] = vzero; }

    // ---- prologue: accA = x(0) partials ----
    {
        const int s_id = dir ? (S_LEN - 1) : 0;
        const bf16* Ax = xT + (size_t)s_id * NBATCH * HDIM + kbase;
#pragma unroll
        for (int mh = 0; mh < 2; mh++) {
            accA[mh][0] = vzero; accA[mh][1] = vzero;
#pragma unroll
            for (int it = 0; it < 2; it++) {
                bf16x8 a = *(const bf16x8*)(Ax + (size_t)(mh * 16 + r) * HDIM + it * 32);
                accA[mh][0] = __builtin_amdgcn_mfma_f32_16x16x32_bf16(a, bx[0][it], accA[mh][0], 0, 0, 0);
                accA[mh][1] = __builtin_amdgcn_mfma_f32_16x16x32_bf16(a, bx[1][it], accA[mh][1], 0, 0, 0);
            }
        }
    }

    for (int t = 0; t < S_LEN; ++t) {
        const int s_idx = dir ? (S_LEN - 1 - t) : t;

        // ---- hoisted mask load: issued here, consumed in update phase ----
        float mt = 0.f;
        if (tid < 256) mt = mask[un * S_LEN + s_idx];

        // ---- issue h(t) loads early (slot t&3), 16B sc1; swept below ----
        const u64* Hp = (const u64*)hbuf
                      + ((size_t)((t & 3) * 2 + dir) * NBATCH) * 256 + (kbase >> 2);
        const u64* hp[2][2];
        u32x4 hv[2][2];
#pragma unroll
        for (int mh = 0; mh < 2; mh++)
#pragma unroll
            for (int it = 0; it < 2; it++) {
                hp[mh][it] = Hp + (size_t)(mh * 16 + r) * 256 + it * 8;
                asm volatile("global_load_dwordx4 %0, %1, off sc1"
                             : "=v"(hv[mh][it]) : "v"(hp[mh][it]));
            }

        // ---- overlap: x(t+1) -> accB (no cross-block dependency) ----
        if (t + 1 < S_LEN) {
            const int s_id = dir ? (S_LEN - 2 - t) : (t + 1);
            const bf16* Ax = xT + (size_t)s_id * NBATCH * HDIM + kbase;
#pragma unroll
            for (int mh = 0; mh < 2; mh++) {
                accB[mh][0] = vzero; accB[mh][1] = vzero;
#pragma unroll
                for (int it = 0; it < 2; it++) {
                    bf16x8 a = *(const bf16x8*)(Ax + (size_t)(mh * 16 + r) * HDIM + it * 32);
                    accB[mh][0] = __builtin_amdgcn_mfma_f32_16x16x32_bf16(a, bx[0][it], accB[mh][0], 0, 0, 0);
                    accB[mh][1] = __builtin_amdgcn_mfma_f32_16x16x32_bf16(a, bx[1][it], accB[mh][1], 0, 0, 0);
                }
            }
        }

        // ---- wait for h loads (ties values through the wait: rule-18-safe) ----
        asm volatile("s_waitcnt vmcnt(0)"
                     : "+v"(hv[0][0]), "+v"(hv[0][1]), "+v"(hv[1][0]), "+v"(hv[1][1])
                     :: "memory");
        __builtin_amdgcn_sched_barrier(0);

        // ---- retry sweeps with s_sleep backoff ----
        {
            int guard = 0;
            while ((stale4(hv[0][0]) | stale4(hv[0][1]) | stale4(hv[1][0]) | stale4(hv[1][1]))
                   && ++guard <= 8192) {
                if (guard > 1) __builtin_amdgcn_s_sleep(2);
#pragma unroll
                for (int mh = 0; mh < 2; mh++)
#pragma unroll
                    for (int it = 0; it < 2; it++)
                        asm volatile("global_load_dwordx4 %0, %1, off sc1"
                                     : "=v"(hv[mh][it]) : "v"(hp[mh][it]));
                asm volatile("s_waitcnt vmcnt(0)"
                             : "+v"(hv[0][0]), "+v"(hv[0][1]), "+v"(hv[1][0]), "+v"(hv[1][1])
                             :: "memory");
                __builtin_amdgcn_sched_barrier(0);
            }
        }

        // ---- h(t) @ Whh accumulated into accA ----
#pragma unroll
        for (int mh = 0; mh < 2; mh++)
#pragma unroll
            for (int it = 0; it < 2; it++) {
                union { u32x4 q; bf16x8 v; } av;
                av.q = hv[mh][it];
                accA[mh][0] = __builtin_amdgcn_mfma_f32_16x16x32_bf16(av.v, bh[0][it], accA[mh][0], 0, 0, 0);
                accA[mh][1] = __builtin_amdgcn_mfma_f32_16x16x32_bf16(av.v, bh[1][it], accA[mh][1], 0, 0, 0);
            }

        // ---- partials -> LDS; f(row,col) = col ^ ((row&7)*4): 2-way exact ----
        {
            float* slab = part + w * 1024;
#pragma unroll
            for (int mh = 0; mh < 2; mh++)
#pragma unroll
                for (int gp = 0; gp < 2; gp++)
#pragma unroll
                    for (int rr = 0; rr < 4; rr++) {
                        const int row = mh * 16 + q * 4 + rr;
                        const int pc = (gp * 16 + r) ^ ((row & 7) * 4);
                        slab[row * 32 + pc] = accA[mh][gp][rr];
                    }
        }
#pragma unroll
        for (int mh = 0; mh < 2; mh++) { accA[mh][0] = accB[mh][0]; accA[mh][1] = accB[mh][1]; }

        // barrier 1: LDS produce -> consume. lgkmcnt only, NO vmcnt drain.
        asm volatile("s_waitcnt lgkmcnt(0)" ::: "memory");
        __builtin_amdgcn_s_barrier();
        asm volatile("" ::: "memory");

        // ---- cell update ----
        if (tid < 256) {
            // reset slot t+2 to sentinel (u64)
            if ((uc & 3) == 0) {
                u64* rdst = (u64*)hbuf
                    + ((size_t)(((t + 2) & 3) * 2 + dir) * NBATCH + un) * 256
                    + ((col0 + uc) >> 2);
                __hip_atomic_store(rdst, SENT64, __ATOMIC_RELAXED, __HIP_MEMORY_SCOPE_AGENT);
            }
            float pf = b0, pi = b1, po = b2, pg = b3;
            const int rowbase = un * 32;
#pragma unroll
            for (int ww = 0; ww < 16; ww++) {
                const float* rowp = part + ww * 1024 + rowbase;
                pf += rowp[(0  + uc) ^ rx];
                pi += rowp[(8  + uc) ^ rx];
                po += rowp[(16 + uc) ^ rx];
                pg += rowp[(24 + uc) ^ rx];
            }
            const float f  = fast_sig(pf);
            const float i  = fast_sig(pi);
            const float o  = fast_sig(po);
            const float ct = fast_tanh(pg);
            creg = f * creg + i * ct;                 // c updated regardless of mask
            const float hnew = o * fast_tanh(creg);
            const float hcar = (mt == 0.f) ? hreg : hnew;
            hreg = hcar;
            // publish h(t+1): gather 4 cols -> u64, lanes uc&3==0 store
            union { bf16 b; unsigned short u; } cv;
            cv.b = (bf16)hcar;
            const unsigned mine  = cv.u;
            const unsigned other = (unsigned)__shfl_xor((int)mine, 1);
            const unsigned pair  = mine | (other << 16);           // cols uc,uc+1 (even lanes)
            const unsigned pair2 = (unsigned)__shfl_xor((int)pair, 2);
            if ((uc & 3) == 0) {
                u64* dst = (u64*)hbuf
                    + ((size_t)(((t + 1) & 3) * 2 + dir) * NBATCH + un) * 256
                    + ((col0 + uc) >> 2);
                __hip_atomic_store(dst, (u64)pair | ((u64)pair2 << 32),
                                   __ATOMIC_RELAXED, __HIP_MEMORY_SCOPE_AGENT);
            }
            // out stores: nontemporal (never re-read; don't thrash L2)
            __builtin_nontemporal_store(hcar * mt,
                &out[((size_t)(un * S_LEN + s_idx)) * 2048 + dir * 1024 + col0 + uc]);
            if (t == S_LEN - 1)
                __builtin_nontemporal_store(hcar,
                    &out[(size_t)NBATCH * S_LEN * 2048 + un * 2048 + dir * 1024 + col0 + uc]);
        }

        // barrier 2: part[] consumed. NO waitcnt — stores drain in background;
        // next step's vmcnt(0) (h-load wait) force-drains them (in-order vmcnt).
        asm volatile("" ::: "memory");
        __builtin_amdgcn_s_barrier();
        asm volatile("" ::: "memory");
    }
}

// ---------------------------------------------------------------------------
// Workspace layout (bytes), total ~50.9 MB:
//   [0,          16777216)  xT    bf16 [256 s][32 n][1024 d]
//   [16777216,   33554432)  wihT  bf16 [8 g][1024 h][1024 d]
//   [33554432,   50331648)  whhT  bf16 [8 g][1024 h][1024 k]
//   [50331648,   50855936)  hbuf  bf16 [4 slot][2 dir][32][1024] (u32 access)
//                           slot 0 zeroed (h(0)=0), slots 1-3 = 0x7F sentinel
// ---------------------------------------------------------------------------
extern "C" void kernel_launch(void* const* d_in, const int* in_sizes, int n_in,
                              void* d_out, int out_size, void* d_ws, size_t ws_size,
                              hipStream_t stream) {
    const float* x    = (const float*)d_in[0];
    const float* mask = (const float*)d_in[1];
    const float* wih  = (const float*)d_in[2];
    const float* whh  = (const float*)d_in[3];
    const float* bias = (const float*)d_in[4];
    float* out = (float*)d_out;

    char* ws = (char*)d_ws;
    bf16*     xT    = (bf16*)(ws);
    bf16*     wihT  = (bf16*)(ws + 16777216);
    bf16*     whhT  = (bf16*)(ws + 33554432);
    unsigned* hbuf  = (unsigned*)(ws + 50331648);

    // slot 0 = zeros (valid h(0)); slots 1-3 = sentinel bytes
    hipMemsetAsync(ws + 50331648, 0x00, 131072, stream);
    hipMemsetAsync(ws + 50331648 + 131072, 0x7F, 393216, stream);

    convert_x<<<NBATCH * S_LEN, 256, 0, stream>>>(x, xT);
    dim3 tb(32, 8);
    convert_transpose_1024<<<dim3(32, 32, 8), tb, 0, stream>>>(wih, wihT);
    convert_transpose_1024<<<dim3(32, 32, 8), tb, 0, stream>>>(whh, whhT);

    lstm_persistent<<<NBLK, 1024, 0, stream>>>(xT, wihT, whhT, mask, bias,
                                               hbuf, out);
}

// Round 2
// 2291.445 us; speedup vs baseline: 1.2856x; 1.2856x over previous
//
#include <hip/hip_runtime.h>
#include <hip/hip_bf16.h>

using bf16 = __hip_bfloat16;
using bf16x8 = __attribute__((ext_vector_type(8))) short;   // 8 bf16 = 4 VGPRs
using f32x4  = __attribute__((ext_vector_type(4))) float;
typedef unsigned long long u64;

#define S_LEN 256
#define NBATCH 32
#define HDIM 1024
#define NBLK 256
#define SENT 0x7F7F7F7Fu   // packed bf16 pair 0x7F7F = 3.3e38: impossible for |h|<1
#define SENT64 0x7F7F7F7F7F7F7F7Full

__device__ __forceinline__ float fast_sig(float x) {
    return __builtin_amdgcn_rcpf(1.f + __expf(-x));
}
__device__ __forceinline__ float fast_tanh(float x) {
    return 1.f - 2.f * __builtin_amdgcn_rcpf(1.f + __expf(2.f * x));
}
__device__ __forceinline__ bool is_stale(u64 v) {
    return ((unsigned)v == SENT) || ((unsigned)(v >> 32) == SENT);
}

// ---------------------------------------------------------------------------
// Convert x (f32, [n][s][d]) -> xT (bf16, [s][n][d]).
// ---------------------------------------------------------------------------
__global__ __launch_bounds__(256) void convert_x(const float* __restrict__ x,
                                                 bf16* __restrict__ xT) {
    const int p = blockIdx.x;          // p = n*256 + s
    const int n = p >> 8;
    const int s = p & 255;
    const float* src = x + (size_t)p * 1024;
    bf16* dst = xT + (size_t)(s * NBATCH + n) * 1024;
#pragma unroll
    for (int j = 0; j < 4; j++) {
        const int d = threadIdx.x + j * 256;
        dst[d] = (bf16)src[d];
    }
}

// ---------------------------------------------------------------------------
// Convert + transpose: 8 matrices of 1024x1024, f32 in, bf16 out,
// out[g][c][r] = in[g][r][c]
// ---------------------------------------------------------------------------
__global__ __launch_bounds__(256) void convert_transpose_1024(const float* __restrict__ in,
                                                              bf16* __restrict__ out) {
    __shared__ float t[32][33];
    const int g  = blockIdx.z;
    const float* A = in  + (size_t)g * 1024 * 1024;
    bf16*        B = out + (size_t)g * 1024 * 1024;
    const int c0 = blockIdx.x * 32;
    const int r0 = blockIdx.y * 32;
    const int tx = threadIdx.x, ty = threadIdx.y;   // (32, 8)
#pragma unroll
    for (int j = 0; j < 32; j += 8)
        t[ty + j][tx] = A[(size_t)(r0 + ty + j) * 1024 + c0 + tx];
    __syncthreads();
#pragma unroll
    for (int j = 0; j < 32; j += 8)
        B[(size_t)(c0 + ty + j) * 1024 + r0 + tx] = (bf16)t[tx][ty + j];
}

// ---------------------------------------------------------------------------
// Persistent BiLSTM — flag-free, self-synchronizing via data sentinels.
// Round-0 structure restored (atomic u64 polls hitting L2, __syncthreads
// barriers, plain out stores). This round's single structural change:
// dir = bi&1 so each direction maps to one XCD parity class under
// round-robin dispatch — halves the publish-invalidate fan-out and the
// per-hbuf-line sharer set. Mask load hoisted to loop top (hides under
// the MFMA phase).
// ---------------------------------------------------------------------------
__global__ __launch_bounds__(1024) void lstm_persistent(
        const bf16* __restrict__ xT,
        const bf16* __restrict__ wihT,
        const bf16* __restrict__ whhT,
        const float* __restrict__ mask,
        const float* __restrict__ bias,
        unsigned* __restrict__ hbuf,    // [4 slot][2 dir][32 n][512] u32 (bf16 pairs)
        float* __restrict__ out) {
    __shared__ float part[16 * 1024];   // 64 KB: slab w = [32 rows][32 cols] swizzled

    const int bi   = blockIdx.x;
    const int dir  = bi & 1;            // XCD-parity localization: dir0=even XCDs, dir1=odd
    const int col0 = ((bi >> 1) & 127) << 3;
    const int tid  = threadIdx.x;
    const int w    = tid >> 6;
    const int lane = tid & 63;
    const int r    = lane & 15;
    const int q    = lane >> 4;
    const int kbase = w * 64 + q * 8;   // this wave's K-slice origin (+quad)

    // ---- pin weights: B-frags for both matrices, both gate-pairs ----
    bf16x8 bx[2][2], bh[2][2];
#pragma unroll
    for (int gp = 0; gp < 2; gp++) {
        const int gate = gp * 2 + (r >> 3);
        const size_t rowoff = ((size_t)((dir * 4 + gate) * 1024 + col0 + (r & 7))) * 1024 + kbase;
#pragma unroll
        for (int it = 0; it < 2; it++) {
            bx[gp][it] = *(const bf16x8*)(wihT + rowoff + it * 32);
            bh[gp][it] = *(const bf16x8*)(whhT + rowoff + it * 32);
        }
    }

    // ---- update-thread state (tid<256 owns (n = tid>>3, c = tid&7)) ----
    const int un = tid >> 3;
    const int uc = tid & 7;
    float creg = 0.f, hreg = 0.f;
    float b0 = 0.f, b1 = 0.f, b2 = 0.f, b3 = 0.f;
    if (tid < 256) {
        const int gb = (dir * 4) * 1024 + col0 + uc;
        b0 = bias[gb];
        b1 = bias[gb + 1024];
        b2 = bias[gb + 2048];
        b3 = bias[gb + 3072];
    }
    const int rx = (un & 7) * 4;        // update-read swizzle

    const f32x4 vzero = {0.f, 0.f, 0.f, 0.f};
    f32x4 accA[2][2], accB[2][2];
#pragma unroll
    for (int mh = 0; mh < 2; mh++) { accB[mh][0] = vzero; accB[mh][1] = vzero; }

    // ---- prologue: accA = x(0) partials ----
    {
        const int s_id = dir ? (S_LEN - 1) : 0;
        const bf16* Ax = xT + (size_t)s_id * NBATCH * HDIM + kbase;
#pragma unroll
        for (int mh = 0; mh < 2; mh++) {
            accA[mh][0] = vzero; accA[mh][1] = vzero;
#pragma unroll
            for (int it = 0; it < 2; it++) {
                bf16x8 a = *(const bf16x8*)(Ax + (size_t)(mh * 16 + r) * HDIM + it * 32);
                accA[mh][0] = __builtin_amdgcn_mfma_f32_16x16x32_bf16(a, bx[0][it], accA[mh][0], 0, 0, 0);
                accA[mh][1] = __builtin_amdgcn_mfma_f32_16x16x32_bf16(a, bx[1][it], accA[mh][1], 0, 0, 0);
            }
        }
    }

    for (int t = 0; t < S_LEN; ++t) {
        const int s_idx = dir ? (S_LEN - 1 - t) : t;

        // ---- hoisted mask load: issued here, consumed in update phase ----
        float mt = 0.f;
        if (tid < 256) mt = mask[un * S_LEN + s_idx];

        // ---- issue h(t) loads early (slot t&3); swept below if stale ----
        const u64* Hp = (const u64*)hbuf
                      + ((size_t)((t & 3) * 2 + dir) * NBATCH) * 256 + (kbase >> 2);
        u64 hv[2][2][2];
#pragma unroll
        for (int mh = 0; mh < 2; mh++)
#pragma unroll
            for (int it = 0; it < 2; it++)
#pragma unroll
                for (int j = 0; j < 2; j++)
                    hv[mh][it][j] = __hip_atomic_load(
                        Hp + (size_t)(mh * 16 + r) * 256 + it * 8 + j,
                        __ATOMIC_RELAXED, __HIP_MEMORY_SCOPE_AGENT);

        // ---- overlap: x(t+1) -> accB (no cross-block dependency) ----
        if (t + 1 < S_LEN) {
            const int s_id = dir ? (S_LEN - 2 - t) : (t + 1);
            const bf16* Ax = xT + (size_t)s_id * NBATCH * HDIM + kbase;
#pragma unroll
            for (int mh = 0; mh < 2; mh++) {
                accB[mh][0] = vzero; accB[mh][1] = vzero;
#pragma unroll
                for (int it = 0; it < 2; it++) {
                    bf16x8 a = *(const bf16x8*)(Ax + (size_t)(mh * 16 + r) * HDIM + it * 32);
                    accB[mh][0] = __builtin_amdgcn_mfma_f32_16x16x32_bf16(a, bx[0][it], accB[mh][0], 0, 0, 0);
                    accB[mh][1] = __builtin_amdgcn_mfma_f32_16x16x32_bf16(a, bx[1][it], accB[mh][1], 0, 0, 0);
                }
            }
        }

        // ---- BATCHED retry sweeps: reload all stale u64s in parallel ----
        {
            int guard = 0;
            while (true) {
                bool stale = false;
#pragma unroll
                for (int mh = 0; mh < 2; mh++)
#pragma unroll
                    for (int it = 0; it < 2; it++)
#pragma unroll
                        for (int j = 0; j < 2; j++)
                            stale |= is_stale(hv[mh][it][j]);
                if (!stale || ++guard > 8192) break;
#pragma unroll
                for (int mh = 0; mh < 2; mh++)
#pragma unroll
                    for (int it = 0; it < 2; it++)
#pragma unroll
                        for (int j = 0; j < 2; j++)
                            if (is_stale(hv[mh][it][j]))
                                hv[mh][it][j] = __hip_atomic_load(
                                    Hp + (size_t)(mh * 16 + r) * 256 + it * 8 + j,
                                    __ATOMIC_RELAXED, __HIP_MEMORY_SCOPE_AGENT);
            }
        }

        // ---- h(t) @ Whh accumulated into accA ----
#pragma unroll
        for (int mh = 0; mh < 2; mh++)
#pragma unroll
            for (int it = 0; it < 2; it++) {
                union { u64 qv[2]; bf16x8 v; } av;
                av.qv[0] = hv[mh][it][0];
                av.qv[1] = hv[mh][it][1];
                accA[mh][0] = __builtin_amdgcn_mfma_f32_16x16x32_bf16(av.v, bh[0][it], accA[mh][0], 0, 0, 0);
                accA[mh][1] = __builtin_amdgcn_mfma_f32_16x16x32_bf16(av.v, bh[1][it], accA[mh][1], 0, 0, 0);
            }

        // ---- partials -> LDS; f(row,col) = col ^ ((row&7)*4): 2-way exact ----
        {
            float* slab = part + w * 1024;
#pragma unroll
            for (int mh = 0; mh < 2; mh++)
#pragma unroll
                for (int gp = 0; gp < 2; gp++)
#pragma unroll
                    for (int rr = 0; rr < 4; rr++) {
                        const int row = mh * 16 + q * 4 + rr;
                        const int pc = (gp * 16 + r) ^ ((row & 7) * 4);
                        slab[row * 32 + pc] = accA[mh][gp][rr];
                    }
        }
#pragma unroll
        for (int mh = 0; mh < 2; mh++) { accA[mh][0] = accB[mh][0]; accA[mh][1] = accB[mh][1]; }
        __syncthreads();

        // ---- cell update ----
        if (tid < 256) {
            // reset slot t+2 to sentinel (u64)
            if ((uc & 3) == 0) {
                u64* rdst = (u64*)hbuf
                    + ((size_t)(((t + 2) & 3) * 2 + dir) * NBATCH + un) * 256
                    + ((col0 + uc) >> 2);
                __hip_atomic_store(rdst, SENT64, __ATOMIC_RELAXED, __HIP_MEMORY_SCOPE_AGENT);
            }
            float pf = b0, pi = b1, po = b2, pg = b3;
            const int rowbase = un * 32;
#pragma unroll
            for (int ww = 0; ww < 16; ww++) {
                const float* rowp = part + ww * 1024 + rowbase;
                pf += rowp[(0  + uc) ^ rx];
                pi += rowp[(8  + uc) ^ rx];
                po += rowp[(16 + uc) ^ rx];
                pg += rowp[(24 + uc) ^ rx];
            }
            const float f  = fast_sig(pf);
            const float i  = fast_sig(pi);
            const float o  = fast_sig(po);
            const float ct = fast_tanh(pg);
            creg = f * creg + i * ct;                 // c updated regardless of mask
            const float hnew = o * fast_tanh(creg);
            const float hcar = (mt == 0.f) ? hreg : hnew;
            hreg = hcar;
            // publish h(t+1): gather 4 cols -> u64, lanes uc&3==0 store
            union { bf16 b; unsigned short u; } cv;
            cv.b = (bf16)hcar;
            const unsigned mine  = cv.u;
            const unsigned other = (unsigned)__shfl_xor((int)mine, 1);
            const unsigned pair  = mine | (other << 16);           // cols uc,uc+1 (even lanes)
            const unsigned pair2 = (unsigned)__shfl_xor((int)pair, 2);
            if ((uc & 3) == 0) {
                u64* dst = (u64*)hbuf
                    + ((size_t)(((t + 1) & 3) * 2 + dir) * NBATCH + un) * 256
                    + ((col0 + uc) >> 2);
                __hip_atomic_store(dst, (u64)pair | ((u64)pair2 << 32),
                                   __ATOMIC_RELAXED, __HIP_MEMORY_SCOPE_AGENT);
            }
            // out stores: cached, flushed at kernel end, nobody reads them
            out[((size_t)(un * S_LEN + s_idx)) * 2048 + dir * 1024 + col0 + uc] = hcar * mt;
            if (t == S_LEN - 1)
                out[(size_t)NBATCH * S_LEN * 2048 + un * 2048 + dir * 1024 + col0 + uc] = hcar;
        }
        __syncthreads();   // part[] consumed; also vmcnt-drains reset+publish
    }
}

// ---------------------------------------------------------------------------
// Workspace layout (bytes), total ~50.9 MB:
//   [0,          16777216)  xT    bf16 [256 s][32 n][1024 d]
//   [16777216,   33554432)  wihT  bf16 [8 g][1024 h][1024 d]
//   [33554432,   50331648)  whhT  bf16 [8 g][1024 h][1024 k]
//   [50331648,   50855936)  hbuf  bf16 [4 slot][2 dir][32][1024] (u32 access)
//                           slot 0 zeroed (h(0)=0), slots 1-3 = 0x7F sentinel
// ---------------------------------------------------------------------------
extern "C" void kernel_launch(void* const* d_in, const int* in_sizes, int n_in,
                              void* d_out, int out_size, void* d_ws, size_t ws_size,
                              hipStream_t stream) {
    const float* x    = (const float*)d_in[0];
    const float* mask = (const float*)d_in[1];
    const float* wih  = (const float*)d_in[2];
    const float* whh  = (const float*)d_in[3];
    const float* bias = (const float*)d_in[4];
    float* out = (float*)d_out;

    char* ws = (char*)d_ws;
    bf16*     xT    = (bf16*)(ws);
    bf16*     wihT  = (bf16*)(ws + 16777216);
    bf16*     whhT  = (bf16*)(ws + 33554432);
    unsigned* hbuf  = (unsigned*)(ws + 50331648);

    // slot 0 = zeros (valid h(0)); slots 1-3 = sentinel bytes
    hipMemsetAsync(ws + 50331648, 0x00, 131072, stream);
    hipMemsetAsync(ws + 50331648 + 131072, 0x7F, 393216, stream);

    convert_x<<<NBATCH * S_LEN, 256, 0, stream>>>(x, xT);
    dim3 tb(32, 8);
    convert_transpose_1024<<<dim3(32, 32, 8), tb, 0, stream>>>(wih, wihT);
    convert_transpose_1024<<<dim3(32, 32, 8), tb, 0, stream>>>(whh, whhT);

    lstm_persistent<<<NBLK, 1024, 0, stream>>>(xT, wihT, whhT, mask, bias,
                                               hbuf, out);
}

// Round 4
// 1942.204 us; speedup vs baseline: 1.5168x; 1.1798x over previous
//
#include <hip/hip_runtime.h>
#include <hip/hip_bf16.h>

using bf16 = __hip_bfloat16;
using bf16x8 = __attribute__((ext_vector_type(8))) short;   // 8 bf16 = 4 VGPRs
using f32x4  = __attribute__((ext_vector_type(4))) float;
typedef unsigned long long u64;

#define S_LEN 256
#define NBATCH 32
#define HDIM 1024
#define NBLK 256
#define SENT 0x7F7F7F7Fu   // packed bf16 pair 0x7F7F = 3.3e38: impossible for |h|<1
#define SENT64 0x7F7F7F7F7F7F7F7Full
#define GSTRIDE (8192ull * 1024ull)   // xh per-gate stride (elems)

__device__ __forceinline__ float fast_sig(float x) {
    return __builtin_amdgcn_rcpf(1.f + __expf(-x));
}
__device__ __forceinline__ float fast_tanh(float x) {
    return 1.f - 2.f * __builtin_amdgcn_rcpf(1.f + __expf(2.f * x));
}
__device__ __forceinline__ bool is_stale(u64 v) {
    return ((unsigned)v == SENT) || ((unsigned)(v >> 32) == SENT);
}

// ---------------------------------------------------------------------------
// Convert x (f32, [n][s][d]) -> xT (bf16, [s][n][d]).  Row sn = s*32+n.
// ---------------------------------------------------------------------------
__global__ __launch_bounds__(256) void convert_x(const float* __restrict__ x,
                                                 bf16* __restrict__ xT) {
    const int p = blockIdx.x;          // p = n*256 + s
    const int n = p >> 8;
    const int s = p & 255;
    const float* src = x + (size_t)p * 1024;
    bf16* dst = xT + (size_t)(s * NBATCH + n) * 1024;
#pragma unroll
    for (int j = 0; j < 4; j++) {
        const int d = threadIdx.x + j * 256;
        dst[d] = (bf16)src[d];
    }
}

// ---------------------------------------------------------------------------
// Convert + transpose: 8 matrices of 1024x1024, f32 in, bf16 out,
// out[g][c][r] = in[g][r][c]
// ---------------------------------------------------------------------------
__global__ __launch_bounds__(256) void convert_transpose_1024(const float* __restrict__ in,
                                                              bf16* __restrict__ out) {
    __shared__ float t[32][33];
    const int g  = blockIdx.z;
    const float* A = in  + (size_t)g * 1024 * 1024;
    bf16*        B = out + (size_t)g * 1024 * 1024;
    const int c0 = blockIdx.x * 32;
    const int r0 = blockIdx.y * 32;
    const int tx = threadIdx.x, ty = threadIdx.y;   // (32, 8)
#pragma unroll
    for (int j = 0; j < 32; j += 8)
        t[ty + j][tx] = A[(size_t)(r0 + ty + j) * 1024 + c0 + tx];
    __syncthreads();
#pragma unroll
    for (int j = 0; j < 32; j += 8)
        B[(size_t)(c0 + ty + j) * 1024 + r0 + tx] = (bf16)t[tx][ty + j];
}

// ---------------------------------------------------------------------------
// xh GEMM: xh[g][sn][h] = xT[sn][:] . wih[g][:][h] + bias[g][h], T out.
// 128x128 tile, BK=64, 256 thr (4 waves, 2x2), reg-staged LDS, chunk-XOR
// swizzle (16B chunk c at row r stores at c^(r&7)).
// ---------------------------------------------------------------------------
template <typename T>
__global__ __launch_bounds__(256) void xh_gemm(
        const bf16* __restrict__ xT,
        const bf16* __restrict__ wihT,
        const float* __restrict__ bias,
        T* __restrict__ xh) {
    __shared__ bf16 At[128 * 64];
    __shared__ bf16 Bt[128 * 64];
    const int g    = blockIdx.z;
    const int row0 = blockIdx.x * 128;
    const int col0 = blockIdx.y * 128;
    const int tid  = threadIdx.x;
    const int lane = tid & 63;
    const int wid  = tid >> 6;
    const int r16  = lane & 15;
    const int q    = lane >> 4;
    const int wr   = (wid >> 1) * 64;
    const int wc   = (wid & 1) * 64;
    const bf16* A = xT;
    const bf16* B = wihT + (size_t)g * 1024 * 1024;

    const f32x4 vzero = {0.f, 0.f, 0.f, 0.f};
    f32x4 acc[4][4];
#pragma unroll
    for (int m = 0; m < 4; m++)
#pragma unroll
        for (int n = 0; n < 4; n++) acc[m][n] = vzero;

    const int srow   = tid >> 3;        // 0..31
    const int skoff  = (tid & 7) * 8;   // k element offset
    const int schunk = tid & 7;         // 16B chunk index

    for (int kt = 0; kt < 16; ++kt) {
#pragma unroll
        for (int inst = 0; inst < 4; inst++) {
            const int rowA = inst * 32 + srow;
            const int sdst = rowA * 64 + ((schunk ^ (rowA & 7)) << 3);
            bf16x8 va = *(const bf16x8*)(A + (size_t)(row0 + rowA) * 1024 + kt * 64 + skoff);
            *(bf16x8*)(At + sdst) = va;
            bf16x8 vb = *(const bf16x8*)(B + (size_t)(col0 + rowA) * 1024 + kt * 64 + skoff);
            *(bf16x8*)(Bt + sdst) = vb;
        }
        __syncthreads();
#pragma unroll
        for (int it = 0; it < 2; it++) {
            bf16x8 af[4], bfr[4];
#pragma unroll
            for (int m = 0; m < 4; m++) {
                const int arow = wr + m * 16 + r16;
                af[m] = *(const bf16x8*)(At + arow * 64 + ((((it << 2) | q) ^ (arow & 7)) << 3));
            }
#pragma unroll
            for (int n = 0; n < 4; n++) {
                const int brow = wc + n * 16 + r16;
                bfr[n] = *(const bf16x8*)(Bt + brow * 64 + ((((it << 2) | q) ^ (brow & 7)) << 3));
            }
#pragma unroll
            for (int m = 0; m < 4; m++)
#pragma unroll
                for (int n = 0; n < 4; n++)
                    acc[m][n] = __builtin_amdgcn_mfma_f32_16x16x32_bf16(af[m], bfr[n], acc[m][n], 0, 0, 0);
        }
        __syncthreads();
    }
    // epilogue: C row = A-row (sn), col = B-row (h); + bias
    T* C = xh + (size_t)g * GSTRIDE;
    float bcol[4];
#pragma unroll
    for (int n = 0; n < 4; n++)
        bcol[n] = bias[g * 1024 + col0 + wc + n * 16 + r16];
#pragma unroll
    for (int m = 0; m < 4; m++)
#pragma unroll
        for (int n = 0; n < 4; n++)
#pragma unroll
            for (int j = 0; j < 4; j++)
                C[(size_t)(row0 + wr + m * 16 + q * 4 + j) * 1024 + col0 + wc + n * 16 + r16]
                    = (T)(acc[m][n][j] + bcol[n]);
}

// ---------------------------------------------------------------------------
// XCD-local persistent BiLSTM recurrence.
// 64 independent chains (32 n x 2 dir). XCD k (= blockIdx%8, round-robin
// dispatch) owns (dir = k&1, batch group ng = k>>1). Its 32 blocks
// (local = blockIdx>>3) each own 32 h-cols x 4 gates. h state lives in a
// per-XCD 4-slot sentinel ring -> publish/poll stays in one L2.
// Wave w: kq = w&3 (K-quarter of 256), ntp = w>>2 (gate). M=16 MFMA with
// 8 real batch rows (rows 8..15 zero, discarded).
// xh (x-part + bias) precomputed; streamed 4 elems/thread/step.
// ---------------------------------------------------------------------------
template <typename T>
__global__ __launch_bounds__(1024) void lstm_rec(
        const bf16* __restrict__ whhT,
        const T* __restrict__ xh,         // [8 g][8192 sn][1024 h]
        const float* __restrict__ mask,
        unsigned* __restrict__ hstate,    // [4 slot][8 xcd][8 n][1024] bf16
        float* __restrict__ out) {
    __shared__ float part[4 * 1024];      // [4 kq][8 n][4 gate][32 gc] f32 = 16 KB

    const int bi    = blockIdx.x;
    const int xcd   = bi & 7;
    const int local = bi >> 3;            // 0..31
    const int dir   = xcd & 1;
    const int ng    = xcd >> 1;           // batch group: n = ng*8 + un
    const int col0  = local * 32;
    const int tid   = threadIdx.x;
    const int w     = tid >> 6;
    const int lane  = tid & 63;
    const int r16   = lane & 15;
    const int q     = lane >> 4;
    const int kq    = w & 3;              // K-quarter [kq*256, kq*256+256)
    const int ntp   = w >> 2;             // gate 0..3

    // ---- pin Whh^T slice: [2 ntl x 16 gc][256 k] per wave = 64 VGPR ----
    bf16x8 bw[2][8];
#pragma unroll
    for (int ntl = 0; ntl < 2; ntl++) {
        const size_t rowoff =
            ((size_t)((dir * 4 + ntp) * 1024 + col0 + ntl * 16 + r16)) * 1024
            + kq * 256 + q * 8;
#pragma unroll
        for (int it = 0; it < 8; it++)
            bw[ntl][it] = *(const bf16x8*)(whhT + rowoff + it * 32);
    }

    // ---- update-thread state: tid<256 owns (un = tid>>5, uc = tid&31) ----
    const int un = tid >> 5;
    const int uc = tid & 31;
    float creg = 0.f, hreg = 0.f;

    const f32x4 vzero = {0.f, 0.f, 0.f, 0.f};

    for (int t = 0; t < S_LEN; ++t) {
        const int s_idx = dir ? (S_LEN - 1 - t) : t;

        // ---- issue xh + mask loads first (HBM latency hides under poll+MFMA) ----
        float xf = 0.f, xi = 0.f, xo = 0.f, xg = 0.f, mt = 0.f;
        if (tid < 256) {
            const size_t xb = ((size_t)(dir * 4) * GSTRIDE)
                            + ((size_t)(s_idx * 32 + ng * 8 + un)) * 1024 + col0 + uc;
            xf = (float)xh[xb];
            xi = (float)xh[xb + GSTRIDE];
            xo = (float)xh[xb + 2 * GSTRIDE];
            xg = (float)xh[xb + 3 * GSTRIDE];
            mt = mask[(ng * 8 + un) * S_LEN + s_idx];
        }

        // ---- poll h(t) from the XCD-local slot: 16 u64 per lane (r16<8) ----
        const int slot = t & 3;
        const u64* Hp = (const u64*)hstate
                      + ((size_t)((slot * 8 + xcd) * 8 + r16)) * 256
                      + kq * 64 + q * 2;
        u64 hv[8][2];
#pragma unroll
        for (int it = 0; it < 8; it++) { hv[it][0] = 0; hv[it][1] = 0; }
        if (r16 < 8) {
#pragma unroll
            for (int it = 0; it < 8; it++)
#pragma unroll
                for (int j = 0; j < 2; j++)
                    hv[it][j] = __hip_atomic_load(Hp + it * 8 + j,
                        __ATOMIC_RELAXED, __HIP_MEMORY_SCOPE_AGENT);
            // batched retry sweeps (L2-local)
            int guard = 0;
            while (true) {
                bool stale = false;
#pragma unroll
                for (int it = 0; it < 8; it++)
#pragma unroll
                    for (int j = 0; j < 2; j++)
                        stale |= is_stale(hv[it][j]);
                if (!stale || ++guard > 8192) break;
#pragma unroll
                for (int it = 0; it < 8; it++)
#pragma unroll
                    for (int j = 0; j < 2; j++)
                        if (is_stale(hv[it][j]))
                            hv[it][j] = __hip_atomic_load(Hp + it * 8 + j,
                                __ATOMIC_RELAXED, __HIP_MEMORY_SCOPE_AGENT);
            }
        }

        // ---- h(t) @ Whh^T for this wave's (kq, gate): 16 MFMAs ----
        f32x4 acc0 = vzero, acc1 = vzero;
#pragma unroll
        for (int it = 0; it < 8; it++) {
            union { u64 qv[2]; bf16x8 v; } av;
            av.qv[0] = hv[it][0];
            av.qv[1] = hv[it][1];
            acc0 = __builtin_amdgcn_mfma_f32_16x16x32_bf16(av.v, bw[0][it], acc0, 0, 0, 0);
            acc1 = __builtin_amdgcn_mfma_f32_16x16x32_bf16(av.v, bw[1][it], acc1, 0, 0, 0);
        }

        // ---- partials -> LDS (rows 0..7 real; lanes<32). 2-way banks = free ----
        if (lane < 32) {
#pragma unroll
            for (int j = 0; j < 4; j++) {
                const int row = q * 4 + j;
                part[kq * 1024 + row * 128 + ntp * 32 + r16]      = acc0[j];
                part[kq * 1024 + row * 128 + ntp * 32 + 16 + r16] = acc1[j];
            }
        }
        __syncthreads();

        // ---- cell update ----
        if (tid < 256) {
            // reset slot t+2 to sentinel (same thread republishes at t+1)
            if ((uc & 3) == 0) {
                u64* rdst = (u64*)hstate
                    + ((size_t)((((t + 2) & 3) * 8 + xcd) * 8 + un)) * 256
                    + ((col0 + uc) >> 2);
                __hip_atomic_store(rdst, SENT64, __ATOMIC_RELAXED, __HIP_MEMORY_SCOPE_AGENT);
            }
            float pf = xf, pi = xi, po = xo, pg = xg;
#pragma unroll
            for (int k2 = 0; k2 < 4; k2++) {
                const float* p = part + k2 * 1024 + un * 128;
                pf += p[uc];
                pi += p[32 + uc];
                po += p[64 + uc];
                pg += p[96 + uc];
            }
            const float f  = fast_sig(pf);
            const float i  = fast_sig(pi);
            const float o  = fast_sig(po);
            const float ct = fast_tanh(pg);
            creg = f * creg + i * ct;                 // c updated regardless of mask
            const float hnew = o * fast_tanh(creg);
            const float hcar = (mt == 0.f) ? hreg : hnew;
            hreg = hcar;
            // publish h(t+1): pack 4 cols -> u64, lanes uc&3==0 store
            union { bf16 b; unsigned short u; } cv;
            cv.b = (bf16)hcar;
            const unsigned mine  = cv.u;
            const unsigned other = (unsigned)__shfl_xor((int)mine, 1);
            const unsigned pair  = mine | (other << 16);
            const unsigned pair2 = (unsigned)__shfl_xor((int)pair, 2);
            if ((uc & 3) == 0) {
                u64* dst = (u64*)hstate
                    + ((size_t)((((t + 1) & 3) * 8 + xcd) * 8 + un)) * 256
                    + ((col0 + uc) >> 2);
                __hip_atomic_store(dst, (u64)pair | ((u64)pair2 << 32),
                                   __ATOMIC_RELAXED, __HIP_MEMORY_SCOPE_AGENT);
            }
            out[((size_t)((ng * 8 + un) * S_LEN + s_idx)) * 2048 + dir * 1024 + col0 + uc]
                = hcar * mt;
            if (t == S_LEN - 1)
                out[(size_t)NBATCH * S_LEN * 2048 + (ng * 8 + un) * 2048 + dir * 1024 + col0 + uc]
                    = hcar;
        }
        __syncthreads();   // part[] consumed
    }
}

// ---------------------------------------------------------------------------
// Fallback: round-2 verified persistent kernel (51 MB workspace, 2291 µs).
// ---------------------------------------------------------------------------
__global__ __launch_bounds__(1024) void lstm_persistent(
        const bf16* __restrict__ xT,
        const bf16* __restrict__ wihT,
        const bf16* __restrict__ whhT,
        const float* __restrict__ mask,
        const float* __restrict__ bias,
        unsigned* __restrict__ hbuf,    // [4 slot][2 dir][32 n][512] u32
        float* __restrict__ out) {
    __shared__ float part[16 * 1024];

    const int bi   = blockIdx.x;
    const int dir  = bi & 1;
    const int col0 = ((bi >> 1) & 127) << 3;
    const int tid  = threadIdx.x;
    const int w    = tid >> 6;
    const int lane = tid & 63;
    const int r    = lane & 15;
    const int q    = lane >> 4;
    const int kbase = w * 64 + q * 8;

    bf16x8 bx[2][2], bh[2][2];
#pragma unroll
    for (int gp = 0; gp < 2; gp++) {
        const int gate = gp * 2 + (r >> 3);
        const size_t rowoff = ((size_t)((dir * 4 + gate) * 1024 + col0 + (r & 7))) * 1024 + kbase;
#pragma unroll
        for (int it = 0; it < 2; it++) {
            bx[gp][it] = *(const bf16x8*)(wihT + rowoff + it * 32);
            bh[gp][it] = *(const bf16x8*)(whhT + rowoff + it * 32);
        }
    }

    const int un = tid >> 3;
    const int uc = tid & 7;
    float creg = 0.f, hreg = 0.f;
    float b0 = 0.f, b1 = 0.f, b2 = 0.f, b3 = 0.f;
    if (tid < 256) {
        const int gb = (dir * 4) * 1024 + col0 + uc;
        b0 = bias[gb];
        b1 = bias[gb + 1024];
        b2 = bias[gb + 2048];
        b3 = bias[gb + 3072];
    }
    const int rx = (un & 7) * 4;

    const f32x4 vzero = {0.f, 0.f, 0.f, 0.f};
    f32x4 accA[2][2], accB[2][2];
#pragma unroll
    for (int mh = 0; mh < 2; mh++) { accB[mh][0] = vzero; accB[mh][1] = vzero; }

    {
        const int s_id = dir ? (S_LEN - 1) : 0;
        const bf16* Ax = xT + (size_t)s_id * NBATCH * HDIM + kbase;
#pragma unroll
        for (int mh = 0; mh < 2; mh++) {
            accA[mh][0] = vzero; accA[mh][1] = vzero;
#pragma unroll
            for (int it = 0; it < 2; it++) {
                bf16x8 a = *(const bf16x8*)(Ax + (size_t)(mh * 16 + r) * HDIM + it * 32);
                accA[mh][0] = __builtin_amdgcn_mfma_f32_16x16x32_bf16(a, bx[0][it], accA[mh][0], 0, 0, 0);
                accA[mh][1] = __builtin_amdgcn_mfma_f32_16x16x32_bf16(a, bx[1][it], accA[mh][1], 0, 0, 0);
            }
        }
    }

    for (int t = 0; t < S_LEN; ++t) {
        const int s_idx = dir ? (S_LEN - 1 - t) : t;
        float mt = 0.f;
        if (tid < 256) mt = mask[un * S_LEN + s_idx];

        const u64* Hp = (const u64*)hbuf
                      + ((size_t)((t & 3) * 2 + dir) * NBATCH) * 256 + (kbase >> 2);
        u64 hv[2][2][2];
#pragma unroll
        for (int mh = 0; mh < 2; mh++)
#pragma unroll
            for (int it = 0; it < 2; it++)
#pragma unroll
                for (int j = 0; j < 2; j++)
                    hv[mh][it][j] = __hip_atomic_load(
                        Hp + (size_t)(mh * 16 + r) * 256 + it * 8 + j,
                        __ATOMIC_RELAXED, __HIP_MEMORY_SCOPE_AGENT);

        if (t + 1 < S_LEN) {
            const int s_id = dir ? (S_LEN - 2 - t) : (t + 1);
            const bf16* Ax = xT + (size_t)s_id * NBATCH * HDIM + kbase;
#pragma unroll
            for (int mh = 0; mh < 2; mh++) {
                accB[mh][0] = vzero; accB[mh][1] = vzero;
#pragma unroll
                for (int it = 0; it < 2; it++) {
                    bf16x8 a = *(const bf16x8*)(Ax + (size_t)(mh * 16 + r) * HDIM + it * 32);
                    accB[mh][0] = __builtin_amdgcn_mfma_f32_16x16x32_bf16(a, bx[0][it], accB[mh][0], 0, 0, 0);
                    accB[mh][1] = __builtin_amdgcn_mfma_f32_16x16x32_bf16(a, bx[1][it], accB[mh][1], 0, 0, 0);
                }
            }
        }

        {
            int guard = 0;
            while (true) {
                bool stale = false;
#pragma unroll
                for (int mh = 0; mh < 2; mh++)
#pragma unroll
                    for (int it = 0; it < 2; it++)
#pragma unroll
                        for (int j = 0; j < 2; j++)
                            stale |= is_stale(hv[mh][it][j]);
                if (!stale || ++guard > 8192) break;
#pragma unroll
                for (int mh = 0; mh < 2; mh++)
#pragma unroll
                    for (int it = 0; it < 2; it++)
#pragma unroll
                        for (int j = 0; j < 2; j++)
                            if (is_stale(hv[mh][it][j]))
                                hv[mh][it][j] = __hip_atomic_load(
                                    Hp + (size_t)(mh * 16 + r) * 256 + it * 8 + j,
                                    __ATOMIC_RELAXED, __HIP_MEMORY_SCOPE_AGENT);
            }
        }

#pragma unroll
        for (int mh = 0; mh < 2; mh++)
#pragma unroll
            for (int it = 0; it < 2; it++) {
                union { u64 qv[2]; bf16x8 v; } av;
                av.qv[0] = hv[mh][it][0];
                av.qv[1] = hv[mh][it][1];
                accA[mh][0] = __builtin_amdgcn_mfma_f32_16x16x32_bf16(av.v, bh[0][it], accA[mh][0], 0, 0, 0);
                accA[mh][1] = __builtin_amdgcn_mfma_f32_16x16x32_bf16(av.v, bh[1][it], accA[mh][1], 0, 0, 0);
            }

        {
            float* slab = part + w * 1024;
#pragma unroll
            for (int mh = 0; mh < 2; mh++)
#pragma unroll
                for (int gp = 0; gp < 2; gp++)
#pragma unroll
                    for (int rr = 0; rr < 4; rr++) {
                        const int row = mh * 16 + q * 4 + rr;
                        const int pc = (gp * 16 + r) ^ ((row & 7) * 4);
                        slab[row * 32 + pc] = accA[mh][gp][rr];
                    }
        }
#pragma unroll
        for (int mh = 0; mh < 2; mh++) { accA[mh][0] = accB[mh][0]; accA[mh][1] = accB[mh][1]; }
        __syncthreads();

        if (tid < 256) {
            if ((uc & 3) == 0) {
                u64* rdst = (u64*)hbuf
                    + ((size_t)(((t + 2) & 3) * 2 + dir) * NBATCH + un) * 256
                    + ((col0 + uc) >> 2);
                __hip_atomic_store(rdst, SENT64, __ATOMIC_RELAXED, __HIP_MEMORY_SCOPE_AGENT);
            }
            float pf = b0, pi = b1, po = b2, pg = b3;
            const int rowbase = un * 32;
#pragma unroll
            for (int ww = 0; ww < 16; ww++) {
                const float* rowp = part + ww * 1024 + rowbase;
                pf += rowp[(0  + uc) ^ rx];
                pi += rowp[(8  + uc) ^ rx];
                po += rowp[(16 + uc) ^ rx];
                pg += rowp[(24 + uc) ^ rx];
            }
            const float f  = fast_sig(pf);
            const float i  = fast_sig(pi);
            const float o  = fast_sig(po);
            const float ct = fast_tanh(pg);
            creg = f * creg + i * ct;
            const float hnew = o * fast_tanh(creg);
            const float hcar = (mt == 0.f) ? hreg : hnew;
            hreg = hcar;
            union { bf16 b; unsigned short u; } cv;
            cv.b = (bf16)hcar;
            const unsigned mine  = cv.u;
            const unsigned other = (unsigned)__shfl_xor((int)mine, 1);
            const unsigned pair  = mine | (other << 16);
            const unsigned pair2 = (unsigned)__shfl_xor((int)pair, 2);
            if ((uc & 3) == 0) {
                u64* dst = (u64*)hbuf
                    + ((size_t)(((t + 1) & 3) * 2 + dir) * NBATCH + un) * 256
                    + ((col0 + uc) >> 2);
                __hip_atomic_store(dst, (u64)pair | ((u64)pair2 << 32),
                                   __ATOMIC_RELAXED, __HIP_MEMORY_SCOPE_AGENT);
            }
            out[((size_t)(un * S_LEN + s_idx)) * 2048 + dir * 1024 + col0 + uc] = hcar * mt;
            if (t == S_LEN - 1)
                out[(size_t)NBATCH * S_LEN * 2048 + un * 2048 + dir * 1024 + col0 + uc] = hcar;
        }
        __syncthreads();
    }
}

// ---------------------------------------------------------------------------
// Workspace layouts (adaptive on ws_size):
//   common: [0,16MB) xT | [16,32MB) wihT | [32,48MB) whhT
//   A (ws >= 319291392): xh f32 [8g][8192][1024] at 48MB, hstate at 318767104
//   B (ws >= 185073664): xh bf16 at 48MB, hstate at 184549376
//   C (else):            round-2 hbuf at 48MB (51 MB total, verified)
// ---------------------------------------------------------------------------
extern "C" void kernel_launch(void* const* d_in, const int* in_sizes, int n_in,
                              void* d_out, int out_size, void* d_ws, size_t ws_size,
                              hipStream_t stream) {
    const float* x    = (const float*)d_in[0];
    const float* mask = (const float*)d_in[1];
    const float* wih  = (const float*)d_in[2];
    const float* whh  = (const float*)d_in[3];
    const float* bias = (const float*)d_in[4];
    float* out = (float*)d_out;

    char* ws = (char*)d_ws;
    bf16* xT   = (bf16*)(ws);
    bf16* wihT = (bf16*)(ws + 16777216);
    bf16* whhT = (bf16*)(ws + 33554432);

    convert_x<<<NBATCH * S_LEN, 256, 0, stream>>>(x, xT);
    dim3 tb(32, 8);
    convert_transpose_1024<<<dim3(32, 32, 8), tb, 0, stream>>>(wih, wihT);
    convert_transpose_1024<<<dim3(32, 32, 8), tb, 0, stream>>>(whh, whhT);

    if (ws_size >= 319291392ull) {
        // Path A: f32 xh
        float*    xh     = (float*)(ws + 50331648);
        unsigned* hstate = (unsigned*)(ws + 318767104);
        hipMemsetAsync((char*)hstate, 0x00, 131072, stream);
        hipMemsetAsync((char*)hstate + 131072, 0x7F, 393216, stream);
        xh_gemm<float><<<dim3(64, 8, 8), 256, 0, stream>>>(xT, wihT, bias, xh);
        lstm_rec<float><<<256, 1024, 0, stream>>>(whhT, xh, mask, hstate, out);
    } else if (ws_size >= 185073664ull) {
        // Path B: bf16 xh
        bf16*     xh     = (bf16*)(ws + 50331648);
        unsigned* hstate = (unsigned*)(ws + 184549376);
        hipMemsetAsync((char*)hstate, 0x00, 131072, stream);
        hipMemsetAsync((char*)hstate + 131072, 0x7F, 393216, stream);
        xh_gemm<bf16><<<dim3(64, 8, 8), 256, 0, stream>>>(xT, wihT, bias, xh);
        lstm_rec<bf16><<<256, 1024, 0, stream>>>(whhT, xh, mask, hstate, out);
    } else {
        // Path C: verified round-2 fused persistent kernel
        unsigned* hbuf = (unsigned*)(ws + 50331648);
        hipMemsetAsync((char*)hbuf, 0x00, 131072, stream);
        hipMemsetAsync((char*)hbuf + 131072, 0x7F, 393216, stream);
        lstm_persistent<<<NBLK, 1024, 0, stream>>>(xT, wihT, whhT, mask, bias,
                                                   hbuf, out);
    }
}

// Round 6
// 1200.415 us; speedup vs baseline: 2.4541x; 1.6179x over previous
//
#include <hip/hip_runtime.h>
#include <hip/hip_bf16.h>

using bf16 = __hip_bfloat16;
using bf16x8 = __attribute__((ext_vector_type(8))) short;   // 8 bf16 = 4 VGPRs
using f32x4  = __attribute__((ext_vector_type(4))) float;
typedef unsigned long long u64;

#define S_LEN 256
#define NBATCH 32
#define HDIM 1024
#define NBLK 256
#define SENT 0x7F7F7F7Fu   // packed bf16 pair 0x7F7F = 3.3e38: impossible for |h|<1
#define SENT64 0x7F7F7F7F7F7F7F7Full
#define GSTRIDE (8192ull * 1024ull)   // xh per-gate stride (elems)

__device__ __forceinline__ float fast_sig(float x) {
    return __builtin_amdgcn_rcpf(1.f + __expf(-x));
}
__device__ __forceinline__ float fast_tanh(float x) {
    return 1.f - 2.f * __builtin_amdgcn_rcpf(1.f + __expf(2.f * x));
}
__device__ __forceinline__ bool is_stale(u64 v) {
    return ((unsigned)v == SENT) || ((unsigned)(v >> 32) == SENT);
}

// ---------------------------------------------------------------------------
// Convert x (f32, [n][s][d]) -> xT (bf16, [s][n][d]).  Row sn = s*32+n.
// ---------------------------------------------------------------------------
__global__ __launch_bounds__(256) void convert_x(const float* __restrict__ x,
                                                 bf16* __restrict__ xT) {
    const int p = blockIdx.x;          // p = n*256 + s
    const int n = p >> 8;
    const int s = p & 255;
    const float* src = x + (size_t)p * 1024;
    bf16* dst = xT + (size_t)(s * NBATCH + n) * 1024;
#pragma unroll
    for (int j = 0; j < 4; j++) {
        const int d = threadIdx.x + j * 256;
        dst[d] = (bf16)src[d];
    }
}

// ---------------------------------------------------------------------------
// Convert + transpose: 8 matrices of 1024x1024, f32 in, bf16 out,
// out[g][c][r] = in[g][r][c]
// ---------------------------------------------------------------------------
__global__ __launch_bounds__(256) void convert_transpose_1024(const float* __restrict__ in,
                                                              bf16* __restrict__ out) {
    __shared__ float t[32][33];
    const int g  = blockIdx.z;
    const float* A = in  + (size_t)g * 1024 * 1024;
    bf16*        B = out + (size_t)g * 1024 * 1024;
    const int c0 = blockIdx.x * 32;
    const int r0 = blockIdx.y * 32;
    const int tx = threadIdx.x, ty = threadIdx.y;   // (32, 8)
#pragma unroll
    for (int j = 0; j < 32; j += 8)
        t[ty + j][tx] = A[(size_t)(r0 + ty + j) * 1024 + c0 + tx];
    __syncthreads();
#pragma unroll
    for (int j = 0; j < 32; j += 8)
        B[(size_t)(c0 + ty + j) * 1024 + r0 + tx] = (bf16)t[tx][ty + j];
}

// ---------------------------------------------------------------------------
// xh GEMM: xh[g][sn][h] = xT[sn][:] . wih[g][:][h] + bias[g][h], T out.
// 128x128 tile, BK=64, 256 thr (4 waves, 2x2), reg-staged LDS, chunk-XOR
// swizzle (16B chunk c at row r stores at c^(r&7)).
// ---------------------------------------------------------------------------
template <typename T>
__global__ __launch_bounds__(256) void xh_gemm(
        const bf16* __restrict__ xT,
        const bf16* __restrict__ wihT,
        const float* __restrict__ bias,
        T* __restrict__ xh) {
    __shared__ bf16 At[128 * 64];
    __shared__ bf16 Bt[128 * 64];
    const int g    = blockIdx.z;
    const int row0 = blockIdx.x * 128;
    const int col0 = blockIdx.y * 128;
    const int tid  = threadIdx.x;
    const int lane = tid & 63;
    const int wid  = tid >> 6;
    const int r16  = lane & 15;
    const int q    = lane >> 4;
    const int wr   = (wid >> 1) * 64;
    const int wc   = (wid & 1) * 64;
    const bf16* A = xT;
    const bf16* B = wihT + (size_t)g * 1024 * 1024;

    const f32x4 vzero = {0.f, 0.f, 0.f, 0.f};
    f32x4 acc[4][4];
#pragma unroll
    for (int m = 0; m < 4; m++)
#pragma unroll
        for (int n = 0; n < 4; n++) acc[m][n] = vzero;

    const int srow   = tid >> 3;        // 0..31
    const int skoff  = (tid & 7) * 8;   // k element offset
    const int schunk = tid & 7;         // 16B chunk index

    for (int kt = 0; kt < 16; ++kt) {
#pragma unroll
        for (int inst = 0; inst < 4; inst++) {
            const int rowA = inst * 32 + srow;
            const int sdst = rowA * 64 + ((schunk ^ (rowA & 7)) << 3);
            bf16x8 va = *(const bf16x8*)(A + (size_t)(row0 + rowA) * 1024 + kt * 64 + skoff);
            *(bf16x8*)(At + sdst) = va;
            bf16x8 vb = *(const bf16x8*)(B + (size_t)(col0 + rowA) * 1024 + kt * 64 + skoff);
            *(bf16x8*)(Bt + sdst) = vb;
        }
        __syncthreads();
#pragma unroll
        for (int it = 0; it < 2; it++) {
            bf16x8 af[4], bfr[4];
#pragma unroll
            for (int m = 0; m < 4; m++) {
                const int arow = wr + m * 16 + r16;
                af[m] = *(const bf16x8*)(At + arow * 64 + ((((it << 2) | q) ^ (arow & 7)) << 3));
            }
#pragma unroll
            for (int n = 0; n < 4; n++) {
                const int brow = wc + n * 16 + r16;
                bfr[n] = *(const bf16x8*)(Bt + brow * 64 + ((((it << 2) | q) ^ (brow & 7)) << 3));
            }
#pragma unroll
            for (int m = 0; m < 4; m++)
#pragma unroll
                for (int n = 0; n < 4; n++)
                    acc[m][n] = __builtin_amdgcn_mfma_f32_16x16x32_bf16(af[m], bfr[n], acc[m][n], 0, 0, 0);
        }
        __syncthreads();
    }
    // epilogue: C row = A-row (sn), col = B-row (h); + bias
    T* C = xh + (size_t)g * GSTRIDE;
    float bcol[4];
#pragma unroll
    for (int n = 0; n < 4; n++)
        bcol[n] = bias[g * 1024 + col0 + wc + n * 16 + r16];
#pragma unroll
    for (int m = 0; m < 4; m++)
#pragma unroll
        for (int n = 0; n < 4; n++)
#pragma unroll
            for (int j = 0; j < 4; j++)
                C[(size_t)(row0 + wr + m * 16 + q * 4 + j) * 1024 + col0 + wc + n * 16 + r16]
                    = (T)(acc[m][n][j] + bcol[n]);
}

// ---------------------------------------------------------------------------
// XCD-local persistent BiLSTM recurrence, flag-gated.
// XCD k (= blockIdx%8) owns (dir = k&1, batch group ng = k>>1); its 32 blocks
// (local = blockIdx>>3) each own 32 h-cols x 4 gates.
// Readiness via a per-XCD 32-flag cache line (poll 128 B, not 16 KB of data).
// Wave w owns K-slice [w*64,w*64+64) x ALL 128 gate-cols -> the block's 16 KB
// h-read has zero redundancy and runs ONCE per step.
// ROUND-6 FIX: the bulk h-read is 4 x __hip_atomic_load(u64) (the primitive
// proven in rounds 0/2/4). Round 5 fused two global_load_dwordx4 in ONE asm
// block with non-early-clobber "=v" outputs -> regalloc aliased load #1's
// dest with load #2's address pair -> garbage h. No inline asm remains.
// Flag validity: flags[local]=t+1 stored by tid0 AFTER the end-of-step
// __syncthreads (per-wave s_waitcnt vmcnt(0) precedes s_barrier), so all
// publish stores are L2-visible before the flag. Flag gate also enforces
// step-lockstep across the group => slot t+2 reset never collides with a
// slot-t read. Per-word sentinels retained as correctness backstop.
// ---------------------------------------------------------------------------
template <typename T>
__global__ __launch_bounds__(1024) void lstm_rec(
        const bf16* __restrict__ whhT,
        const T* __restrict__ xh,         // [8 g][8192 sn][1024 h]
        const float* __restrict__ mask,
        unsigned* __restrict__ hstate,    // [4 slot][8 xcd][8 n][1024] bf16
        unsigned* __restrict__ flags,     // [8 xcd][32 local] u32, step counter
        float* __restrict__ out) {
    __shared__ float part[16 * 1024];     // [16 w][8 n][4 gate][32 col] f32 = 64 KB

    const int bi    = blockIdx.x;
    const int xcd   = bi & 7;
    const int local = bi >> 3;            // 0..31
    const int dir   = xcd & 1;
    const int ng    = xcd >> 1;           // batch group: n = ng*8 + un
    const int col0  = local * 32;
    const int tid   = threadIdx.x;
    const int w     = tid >> 6;           // wave 0..15 -> K-slice w*64
    const int lane  = tid & 63;
    const int r16   = lane & 15;
    const int q     = lane >> 4;
    const int kbase = w * 64;

    // ---- pin Whh^T: [8 colTile c][2 it] frags = 64 VGPR.
    //      c: gate = c>>1, colsub = (c&1)*16; K: kbase + it*32 + q*8 ----
    bf16x8 bw[8][2];
#pragma unroll
    for (int c = 0; c < 8; c++) {
        const size_t rowoff =
            ((size_t)((dir * 4 + (c >> 1)) * 1024 + col0 + (c & 1) * 16 + r16)) * 1024
            + kbase + q * 8;
#pragma unroll
        for (int it = 0; it < 2; it++)
            bw[c][it] = *(const bf16x8*)(whhT + rowoff + it * 32);
    }

    // ---- update-thread state: tid<256 owns (un = tid>>5, uc = tid&31) ----
    const int un = tid >> 5;
    const int uc = tid & 31;
    float creg = 0.f, hreg = 0.f;

    const unsigned* fp = flags + xcd * 32 + (lane & 31);
    const f32x4 vzero = {0.f, 0.f, 0.f, 0.f};

    for (int t = 0; t < S_LEN; ++t) {
        const int s_idx = dir ? (S_LEN - 1 - t) : t;

        // ---- issue xh + mask loads first (HBM latency hides under flag wait) ----
        float xf = 0.f, xi = 0.f, xo = 0.f, xg = 0.f, mt = 0.f;
        if (tid < 256) {
            const size_t xb = ((size_t)(dir * 4) * GSTRIDE)
                            + ((size_t)(s_idx * 32 + ng * 8 + un)) * 1024 + col0 + uc;
            xf = (float)xh[xb];
            xi = (float)xh[xb + GSTRIDE];
            xo = (float)xh[xb + 2 * GSTRIDE];
            xg = (float)xh[xb + 3 * GSTRIDE];
            mt = mask[(ng * 8 + un) * S_LEN + s_idx];
        }

        // ---- flag wait: one 128 B line per XCD ----
        {
            int fg = 0;
            while (true) {
                const unsigned fl = __hip_atomic_load(fp,
                    __ATOMIC_RELAXED, __HIP_MEMORY_SCOPE_AGENT);
                if (__all((int)fl >= t) || ++fg > (1 << 20)) break;
            }
        }

        // ---- bulk h read, once: lanes r16<8 read 32 B of row n=r16 ----
        u64 hq[4];
        hq[0] = 0; hq[1] = 0; hq[2] = 0; hq[3] = 0;
        const u64* Hq = (const u64*)hstate
            + ((size_t)(((t & 3) * 8 + xcd) * 8 + r16)) * 256
            + (kbase >> 2) + q * 2;
        if (r16 < 8) {
            // u64 offsets 0,1 = k [kbase+q*8, +8); offsets 8,9 = k +32 elems
            hq[0] = __hip_atomic_load(Hq,     __ATOMIC_RELAXED, __HIP_MEMORY_SCOPE_AGENT);
            hq[1] = __hip_atomic_load(Hq + 1, __ATOMIC_RELAXED, __HIP_MEMORY_SCOPE_AGENT);
            hq[2] = __hip_atomic_load(Hq + 8, __ATOMIC_RELAXED, __HIP_MEMORY_SCOPE_AGENT);
            hq[3] = __hip_atomic_load(Hq + 9, __ATOMIC_RELAXED, __HIP_MEMORY_SCOPE_AGENT);
            // sentinel backstop (cold: flag gate makes staleness ~impossible)
            int guard = 0;
            while (true) {
                const bool st = is_stale(hq[0]) | is_stale(hq[1])
                              | is_stale(hq[2]) | is_stale(hq[3]);
                if (!st || ++guard > 8192) break;
                if (is_stale(hq[0]))
                    hq[0] = __hip_atomic_load(Hq,     __ATOMIC_RELAXED, __HIP_MEMORY_SCOPE_AGENT);
                if (is_stale(hq[1]))
                    hq[1] = __hip_atomic_load(Hq + 1, __ATOMIC_RELAXED, __HIP_MEMORY_SCOPE_AGENT);
                if (is_stale(hq[2]))
                    hq[2] = __hip_atomic_load(Hq + 8, __ATOMIC_RELAXED, __HIP_MEMORY_SCOPE_AGENT);
                if (is_stale(hq[3]))
                    hq[3] = __hip_atomic_load(Hq + 9, __ATOMIC_RELAXED, __HIP_MEMORY_SCOPE_AGENT);
            }
        }

        // ---- h(t) @ Whh^T: 16 MFMAs, partials -> LDS as we go ----
        union { u64 qv[2]; bf16x8 v; } av0, av1;
        av0.qv[0] = hq[0]; av0.qv[1] = hq[1];   // k = kbase + q*8 .. +7
        av1.qv[0] = hq[2]; av1.qv[1] = hq[3];   // k = kbase + 32 + q*8 .. +7
#pragma unroll
        for (int c = 0; c < 8; c++) {
            f32x4 a = vzero;
            a = __builtin_amdgcn_mfma_f32_16x16x32_bf16(av0.v, bw[c][0], a, 0, 0, 0);
            a = __builtin_amdgcn_mfma_f32_16x16x32_bf16(av1.v, bw[c][1], a, 0, 0, 0);
            if (lane < 32) {
#pragma unroll
                for (int j = 0; j < 4; j++)
                    part[w * 1024 + (q * 4 + j) * 128 + (c >> 1) * 32 + (c & 1) * 16 + r16]
                        = a[j];
            }
        }
        __syncthreads();

        // ---- cell update ----
        if (tid < 256) {
            // reset slot t+2 to sentinel (lockstep: nobody reads slot t+2 now)
            if ((uc & 3) == 0) {
                u64* rdst = (u64*)hstate
                    + ((size_t)((((t + 2) & 3) * 8 + xcd) * 8 + un)) * 256
                    + ((col0 + uc) >> 2);
                __hip_atomic_store(rdst, SENT64, __ATOMIC_RELAXED, __HIP_MEMORY_SCOPE_AGENT);
            }
            float pf = xf, pi = xi, po = xo, pg = xg;
#pragma unroll
            for (int ww = 0; ww < 16; ww++) {
                const float* p = part + ww * 1024 + un * 128;
                pf += p[uc];
                pi += p[32 + uc];
                po += p[64 + uc];
                pg += p[96 + uc];
            }
            const float f  = fast_sig(pf);
            const float i  = fast_sig(pi);
            const float o  = fast_sig(po);
            const float ct = fast_tanh(pg);
            creg = f * creg + i * ct;                 // c updated regardless of mask
            const float hnew = o * fast_tanh(creg);
            const float hcar = (mt == 0.f) ? hreg : hnew;
            hreg = hcar;
            // publish h(t+1): pack 4 cols -> u64, lanes uc&3==0 store
            union { bf16 b; unsigned short u; } cv;
            cv.b = (bf16)hcar;
            const unsigned mine  = cv.u;
            const unsigned other = (unsigned)__shfl_xor((int)mine, 1);
            const unsigned pair  = mine | (other << 16);
            const unsigned pair2 = (unsigned)__shfl_xor((int)pair, 2);
            if ((uc & 3) == 0) {
                u64* dst = (u64*)hstate
                    + ((size_t)((((t + 1) & 3) * 8 + xcd) * 8 + un)) * 256
                    + ((col0 + uc) >> 2);
                __hip_atomic_store(dst, (u64)pair | ((u64)pair2 << 32),
                                   __ATOMIC_RELAXED, __HIP_MEMORY_SCOPE_AGENT);
            }
            out[((size_t)((ng * 8 + un) * S_LEN + s_idx)) * 2048 + dir * 1024 + col0 + uc]
                = hcar * mt;
            if (t == S_LEN - 1)
                out[(size_t)NBATCH * S_LEN * 2048 + (ng * 8 + un) * 2048 + dir * 1024 + col0 + uc]
                    = hcar;
        }
        __syncthreads();   // part[] consumed; per-wave vmcnt(0) drains publishes

        // ---- signal: this block's h(t+1) is L2-visible ----
        if (tid == 0)
            __hip_atomic_store(flags + xcd * 32 + local, (unsigned)(t + 1),
                               __ATOMIC_RELAXED, __HIP_MEMORY_SCOPE_AGENT);
    }
}

// ---------------------------------------------------------------------------
// Fallback: round-2 verified persistent kernel (51 MB workspace, 2291 µs).
// ---------------------------------------------------------------------------
__global__ __launch_bounds__(1024) void lstm_persistent(
        const bf16* __restrict__ xT,
        const bf16* __restrict__ wihT,
        const bf16* __restrict__ whhT,
        const float* __restrict__ mask,
        const float* __restrict__ bias,
        unsigned* __restrict__ hbuf,    // [4 slot][2 dir][32 n][512] u32
        float* __restrict__ out) {
    __shared__ float part[16 * 1024];

    const int bi   = blockIdx.x;
    const int dir  = bi & 1;
    const int col0 = ((bi >> 1) & 127) << 3;
    const int tid  = threadIdx.x;
    const int w    = tid >> 6;
    const int lane = tid & 63;
    const int r    = lane & 15;
    const int q    = lane >> 4;
    const int kbase = w * 64 + q * 8;

    bf16x8 bx[2][2], bh[2][2];
#pragma unroll
    for (int gp = 0; gp < 2; gp++) {
        const int gate = gp * 2 + (r >> 3);
        const size_t rowoff = ((size_t)((dir * 4 + gate) * 1024 + col0 + (r & 7))) * 1024 + kbase;
#pragma unroll
        for (int it = 0; it < 2; it++) {
            bx[gp][it] = *(const bf16x8*)(wihT + rowoff + it * 32);
            bh[gp][it] = *(const bf16x8*)(whhT + rowoff + it * 32);
        }
    }

    const int un = tid >> 3;
    const int uc = tid & 7;
    float creg = 0.f, hreg = 0.f;
    float b0 = 0.f, b1 = 0.f, b2 = 0.f, b3 = 0.f;
    if (tid < 256) {
        const int gb = (dir * 4) * 1024 + col0 + uc;
        b0 = bias[gb];
        b1 = bias[gb + 1024];
        b2 = bias[gb + 2048];
        b3 = bias[gb + 3072];
    }
    const int rx = (un & 7) * 4;

    const f32x4 vzero = {0.f, 0.f, 0.f, 0.f};
    f32x4 accA[2][2], accB[2][2];
#pragma unroll
    for (int mh = 0; mh < 2; mh++) { accB[mh][0] = vzero; accB[mh][1] = vzero; }

    {
        const int s_id = dir ? (S_LEN - 1) : 0;
        const bf16* Ax = xT + (size_t)s_id * NBATCH * HDIM + kbase;
#pragma unroll
        for (int mh = 0; mh < 2; mh++) {
            accA[mh][0] = vzero; accA[mh][1] = vzero;
#pragma unroll
            for (int it = 0; it < 2; it++) {
                bf16x8 a = *(const bf16x8*)(Ax + (size_t)(mh * 16 + r) * HDIM + it * 32);
                accA[mh][0] = __builtin_amdgcn_mfma_f32_16x16x32_bf16(a, bx[0][it], accA[mh][0], 0, 0, 0);
                accA[mh][1] = __builtin_amdgcn_mfma_f32_16x16x32_bf16(a, bx[1][it], accA[mh][1], 0, 0, 0);
            }
        }
    }

    for (int t = 0; t < S_LEN; ++t) {
        const int s_idx = dir ? (S_LEN - 1 - t) : t;
        float mt = 0.f;
        if (tid < 256) mt = mask[un * S_LEN + s_idx];

        const u64* Hp = (const u64*)hbuf
                      + ((size_t)((t & 3) * 2 + dir) * NBATCH) * 256 + (kbase >> 2);
        u64 hv[2][2][2];
#pragma unroll
        for (int mh = 0; mh < 2; mh++)
#pragma unroll
            for (int it = 0; it < 2; it++)
#pragma unroll
                for (int j = 0; j < 2; j++)
                    hv[mh][it][j] = __hip_atomic_load(
                        Hp + (size_t)(mh * 16 + r) * 256 + it * 8 + j,
                        __ATOMIC_RELAXED, __HIP_MEMORY_SCOPE_AGENT);

        if (t + 1 < S_LEN) {
            const int s_id = dir ? (S_LEN - 2 - t) : (t + 1);
            const bf16* Ax = xT + (size_t)s_id * NBATCH * HDIM + kbase;
#pragma unroll
            for (int mh = 0; mh < 2; mh++) {
                accB[mh][0] = vzero; accB[mh][1] = vzero;
#pragma unroll
                for (int it = 0; it < 2; it++) {
                    bf16x8 a = *(const bf16x8*)(Ax + (size_t)(mh * 16 + r) * HDIM + it * 32);
                    accB[mh][0] = __builtin_amdgcn_mfma_f32_16x16x32_bf16(a, bx[0][it], accB[mh][0], 0, 0, 0);
                    accB[mh][1] = __builtin_amdgcn_mfma_f32_16x16x32_bf16(a, bx[1][it], accB[mh][1], 0, 0, 0);
                }
            }
        }

        {
            int guard = 0;
            while (true) {
                bool stale = false;
#pragma unroll
                for (int mh = 0; mh < 2; mh++)
#pragma unroll
                    for (int it = 0; it < 2; it++)
#pragma unroll
                        for (int j = 0; j < 2; j++)
                            stale |= is_stale(hv[mh][it][j]);
                if (!stale || ++guard > 8192) break;
#pragma unroll
                for (int mh = 0; mh < 2; mh++)
#pragma unroll
                    for (int it = 0; it < 2; it++)
#pragma unroll
                        for (int j = 0; j < 2; j++)
                            if (is_stale(hv[mh][it][j]))
                                hv[mh][it][j] = __hip_atomic_load(
                                    Hp + (size_t)(mh * 16 + r) * 256 + it * 8 + j,
                                    __ATOMIC_RELAXED, __HIP_MEMORY_SCOPE_AGENT);
            }
        }

#pragma unroll
        for (int mh = 0; mh < 2; mh++)
#pragma unroll
            for (int it = 0; it < 2; it++) {
                union { u64 qv[2]; bf16x8 v; } av;
                av.qv[0] = hv[mh][it][0];
                av.qv[1] = hv[mh][it][1];
                accA[mh][0] = __builtin_amdgcn_mfma_f32_16x16x32_bf16(av.v, bh[0][it], accA[mh][0], 0, 0, 0);
                accA[mh][1] = __builtin_amdgcn_mfma_f32_16x16x32_bf16(av.v, bh[1][it], accA[mh][1], 0, 0, 0);
            }

        {
            float* slab = part + w * 1024;
#pragma unroll
            for (int mh = 0; mh < 2; mh++)
#pragma unroll
                for (int gp = 0; gp < 2; gp++)
#pragma unroll
                    for (int rr = 0; rr < 4; rr++) {
                        const int row = mh * 16 + q * 4 + rr;
                        const int pc = (gp * 16 + r) ^ ((row & 7) * 4);
                        slab[row * 32 + pc] = accA[mh][gp][rr];
                    }
        }
#pragma unroll
        for (int mh = 0; mh < 2; mh++) { accA[mh][0] = accB[mh][0]; accA[mh][1] = accB[mh][1]; }
        __syncthreads();

        if (tid < 256) {
            if ((uc & 3) == 0) {
                u64* rdst = (u64*)hbuf
                    + ((size_t)(((t + 2) & 3) * 2 + dir) * NBATCH + un) * 256
                    + ((col0 + uc) >> 2);
                __hip_atomic_store(rdst, SENT64, __ATOMIC_RELAXED, __HIP_MEMORY_SCOPE_AGENT);
            }
            float pf = b0, pi = b1, po = b2, pg = b3;
            const int rowbase = un * 32;
#pragma unroll
            for (int ww = 0; ww < 16; ww++) {
                const float* rowp = part + ww * 1024 + rowbase;
                pf += rowp[(0  + uc) ^ rx];
                pi += rowp[(8  + uc) ^ rx];
                po += rowp[(16 + uc) ^ rx];
                pg += rowp[(24 + uc) ^ rx];
            }
            const float f  = fast_sig(pf);
            const float i  = fast_sig(pi);
            const float o  = fast_sig(po);
            const float ct = fast_tanh(pg);
            creg = f * creg + i * ct;
            const float hnew = o * fast_tanh(creg);
            const float hcar = (mt == 0.f) ? hreg : hnew;
            hreg = hcar;
            union { bf16 b; unsigned short u; } cv;
            cv.b = (bf16)hcar;
            const unsigned mine  = cv.u;
            const unsigned other = (unsigned)__shfl_xor((int)mine, 1);
            const unsigned pair  = mine | (other << 16);
            const unsigned pair2 = (unsigned)__shfl_xor((int)pair, 2);
            if ((uc & 3) == 0) {
                u64* dst = (u64*)hbuf
                    + ((size_t)(((t + 1) & 3) * 2 + dir) * NBATCH + un) * 256
                    + ((col0 + uc) >> 2);
                __hip_atomic_store(dst, (u64)pair | ((u64)pair2 << 32),
                                   __ATOMIC_RELAXED, __HIP_MEMORY_SCOPE_AGENT);
            }
            out[((size_t)(un * S_LEN + s_idx)) * 2048 + dir * 1024 + col0 + uc] = hcar * mt;
            if (t == S_LEN - 1)
                out[(size_t)NBATCH * S_LEN * 2048 + un * 2048 + dir * 1024 + col0 + uc] = hcar;
        }
        __syncthreads();
    }
}

// ---------------------------------------------------------------------------
// Workspace layouts (adaptive on ws_size):
//   common: [0,16MB) xT | [16,32MB) wihT | [32,48MB) whhT
//   A (ws >= 319292416): xh f32 at 48MB, hstate at 318767104, flags +524288
//   B (ws >= 185074688): xh bf16 at 48MB, hstate at 184549376, flags +524288
//   C (else):            round-2 hbuf at 48MB (51 MB total, verified)
// ---------------------------------------------------------------------------
extern "C" void kernel_launch(void* const* d_in, const int* in_sizes, int n_in,
                              void* d_out, int out_size, void* d_ws, size_t ws_size,
                              hipStream_t stream) {
    const float* x    = (const float*)d_in[0];
    const float* mask = (const float*)d_in[1];
    const float* wih  = (const float*)d_in[2];
    const float* whh  = (const float*)d_in[3];
    const float* bias = (const float*)d_in[4];
    float* out = (float*)d_out;

    char* ws = (char*)d_ws;
    bf16* xT   = (bf16*)(ws);
    bf16* wihT = (bf16*)(ws + 16777216);
    bf16* whhT = (bf16*)(ws + 33554432);

    convert_x<<<NBATCH * S_LEN, 256, 0, stream>>>(x, xT);
    dim3 tb(32, 8);
    convert_transpose_1024<<<dim3(32, 32, 8), tb, 0, stream>>>(wih, wihT);
    convert_transpose_1024<<<dim3(32, 32, 8), tb, 0, stream>>>(whh, whhT);

    if (ws_size >= 319292416ull) {
        // Path A: f32 xh
        float*    xh     = (float*)(ws + 50331648);
        unsigned* hstate = (unsigned*)(ws + 318767104);
        unsigned* flags  = (unsigned*)(ws + 318767104 + 524288);
        hipMemsetAsync((char*)hstate, 0x00, 131072, stream);
        hipMemsetAsync((char*)hstate + 131072, 0x7F, 393216, stream);
        hipMemsetAsync((char*)flags, 0x00, 1024, stream);
        xh_gemm<float><<<dim3(64, 8, 8), 256, 0, stream>>>(xT, wihT, bias, xh);
        lstm_rec<float><<<256, 1024, 0, stream>>>(whhT, xh, mask, hstate, flags, out);
    } else if (ws_size >= 185074688ull) {
        // Path B: bf16 xh
        bf16*     xh     = (bf16*)(ws + 50331648);
        unsigned* hstate = (unsigned*)(ws + 184549376);
        unsigned* flags  = (unsigned*)(ws + 184549376 + 524288);
        hipMemsetAsync((char*)hstate, 0x00, 131072, stream);
        hipMemsetAsync((char*)hstate + 131072, 0x7F, 393216, stream);
        hipMemsetAsync((char*)flags, 0x00, 1024, stream);
        xh_gemm<bf16><<<dim3(64, 8, 8), 256, 0, stream>>>(xT, wihT, bias, xh);
        lstm_rec<bf16><<<256, 1024, 0, stream>>>(whhT, xh, mask, hstate, flags, out);
    } else {
        // Path C: verified round-2 fused persistent kernel
        unsigned* hbuf = (unsigned*)(ws + 50331648);
        hipMemsetAsync((char*)hbuf, 0x00, 131072, stream);
        hipMemsetAsync((char*)hbuf + 131072, 0x7F, 393216, stream);
        lstm_persistent<<<NBLK, 1024, 0, stream>>>(xT, wihT, whhT, mask, bias,
                                                   hbuf, out);
    }
}

// Round 7
// 1200.219 us; speedup vs baseline: 2.4545x; 1.0002x over previous
//
#include <hip/hip_runtime.h>
#include <hip/hip_bf16.h>

using bf16 = __hip_bfloat16;
using bf16x8 = __attribute__((ext_vector_type(8))) short;   // 8 bf16 = 4 VGPRs
using f32x4  = __attribute__((ext_vector_type(4))) float;
typedef unsigned long long u64;

#define S_LEN 256
#define NBATCH 32
#define HDIM 1024
#define NBLK 256
#define SENT 0x7F7F7F7Fu   // packed bf16 pair 0x7F7F = 3.3e38: impossible for |h|<1
#define SENT64 0x7F7F7F7F7F7F7F7Full
#define GSTRIDE (8192ull * 1024ull)   // xh per-gate stride (elems)

__device__ __forceinline__ float fast_sig(float x) {
    return __builtin_amdgcn_rcpf(1.f + __expf(-x));
}
__device__ __forceinline__ float fast_tanh(float x) {
    return 1.f - 2.f * __builtin_amdgcn_rcpf(1.f + __expf(2.f * x));
}
__device__ __forceinline__ bool is_stale(u64 v) {
    return ((unsigned)v == SENT) || ((unsigned)(v >> 32) == SENT);
}

// ---------------------------------------------------------------------------
// Convert x (f32, [n][s][d]) -> xT (bf16, [s][n][d]).  Row sn = s*32+n.
// ---------------------------------------------------------------------------
__global__ __launch_bounds__(256) void convert_x(const float* __restrict__ x,
                                                 bf16* __restrict__ xT) {
    const int p = blockIdx.x;          // p = n*256 + s
    const int n = p >> 8;
    const int s = p & 255;
    const float* src = x + (size_t)p * 1024;
    bf16* dst = xT + (size_t)(s * NBATCH + n) * 1024;
#pragma unroll
    for (int j = 0; j < 4; j++) {
        const int d = threadIdx.x + j * 256;
        dst[d] = (bf16)src[d];
    }
}

// ---------------------------------------------------------------------------
// Convert + transpose: 8 matrices of 1024x1024, f32 in, bf16 out,
// out[g][c][r] = in[g][r][c]
// ---------------------------------------------------------------------------
__global__ __launch_bounds__(256) void convert_transpose_1024(const float* __restrict__ in,
                                                              bf16* __restrict__ out) {
    __shared__ float t[32][33];
    const int g  = blockIdx.z;
    const float* A = in  + (size_t)g * 1024 * 1024;
    bf16*        B = out + (size_t)g * 1024 * 1024;
    const int c0 = blockIdx.x * 32;
    const int r0 = blockIdx.y * 32;
    const int tx = threadIdx.x, ty = threadIdx.y;   // (32, 8)
#pragma unroll
    for (int j = 0; j < 32; j += 8)
        t[ty + j][tx] = A[(size_t)(r0 + ty + j) * 1024 + c0 + tx];
    __syncthreads();
#pragma unroll
    for (int j = 0; j < 32; j += 8)
        B[(size_t)(c0 + ty + j) * 1024 + r0 + tx] = (bf16)t[tx][ty + j];
}

// ---------------------------------------------------------------------------
// xh GEMM: xh[g][sn][h] = xT[sn][:] . wih[g][:][h] + bias[g][h], T out.
// 128x128 tile, BK=64, 256 thr (4 waves, 2x2), reg-staged LDS, chunk-XOR
// swizzle (16B chunk c at row r stores at c^(r&7)).
// ---------------------------------------------------------------------------
template <typename T>
__global__ __launch_bounds__(256) void xh_gemm(
        const bf16* __restrict__ xT,
        const bf16* __restrict__ wihT,
        const float* __restrict__ bias,
        T* __restrict__ xh) {
    __shared__ bf16 At[128 * 64];
    __shared__ bf16 Bt[128 * 64];
    const int g    = blockIdx.z;
    const int row0 = blockIdx.x * 128;
    const int col0 = blockIdx.y * 128;
    const int tid  = threadIdx.x;
    const int lane = tid & 63;
    const int wid  = tid >> 6;
    const int r16  = lane & 15;
    const int q    = lane >> 4;
    const int wr   = (wid >> 1) * 64;
    const int wc   = (wid & 1) * 64;
    const bf16* A = xT;
    const bf16* B = wihT + (size_t)g * 1024 * 1024;

    const f32x4 vzero = {0.f, 0.f, 0.f, 0.f};
    f32x4 acc[4][4];
#pragma unroll
    for (int m = 0; m < 4; m++)
#pragma unroll
        for (int n = 0; n < 4; n++) acc[m][n] = vzero;

    const int srow   = tid >> 3;        // 0..31
    const int skoff  = (tid & 7) * 8;   // k element offset
    const int schunk = tid & 7;         // 16B chunk index

    for (int kt = 0; kt < 16; ++kt) {
#pragma unroll
        for (int inst = 0; inst < 4; inst++) {
            const int rowA = inst * 32 + srow;
            const int sdst = rowA * 64 + ((schunk ^ (rowA & 7)) << 3);
            bf16x8 va = *(const bf16x8*)(A + (size_t)(row0 + rowA) * 1024 + kt * 64 + skoff);
            *(bf16x8*)(At + sdst) = va;
            bf16x8 vb = *(const bf16x8*)(B + (size_t)(col0 + rowA) * 1024 + kt * 64 + skoff);
            *(bf16x8*)(Bt + sdst) = vb;
        }
        __syncthreads();
#pragma unroll
        for (int it = 0; it < 2; it++) {
            bf16x8 af[4], bfr[4];
#pragma unroll
            for (int m = 0; m < 4; m++) {
                const int arow = wr + m * 16 + r16;
                af[m] = *(const bf16x8*)(At + arow * 64 + ((((it << 2) | q) ^ (arow & 7)) << 3));
            }
#pragma unroll
            for (int n = 0; n < 4; n++) {
                const int brow = wc + n * 16 + r16;
                bfr[n] = *(const bf16x8*)(Bt + brow * 64 + ((((it << 2) | q) ^ (brow & 7)) << 3));
            }
#pragma unroll
            for (int m = 0; m < 4; m++)
#pragma unroll
                for (int n = 0; n < 4; n++)
                    acc[m][n] = __builtin_amdgcn_mfma_f32_16x16x32_bf16(af[m], bfr[n], acc[m][n], 0, 0, 0);
        }
        __syncthreads();
    }
    // epilogue: C row = A-row (sn), col = B-row (h); + bias
    T* C = xh + (size_t)g * GSTRIDE;
    float bcol[4];
#pragma unroll
    for (int n = 0; n < 4; n++)
        bcol[n] = bias[g * 1024 + col0 + wc + n * 16 + r16];
#pragma unroll
    for (int m = 0; m < 4; m++)
#pragma unroll
        for (int n = 0; n < 4; n++)
#pragma unroll
            for (int j = 0; j < 4; j++)
                C[(size_t)(row0 + wr + m * 16 + q * 4 + j) * 1024 + col0 + wc + n * 16 + r16]
                    = (T)(acc[m][n][j] + bcol[n]);
}

// ---------------------------------------------------------------------------
// XCD-local persistent BiLSTM recurrence, flag-gated.
// XCD k (= blockIdx%8) owns (dir = k&1, batch group ng = k>>1); its 32 blocks
// (local = blockIdx>>3) each own 32 h-cols x 4 gates.
// Readiness via a per-XCD 32-flag cache line; bulk h read once per step
// (4 x u64 atomic loads, gate-dedup wave layout); per-word sentinel backstop.
// ROUND-7 FIX: __launch_bounds__(1024, 4) = 4 waves/SIMD = 1 block/CU ->
// VGPR budget 128/wave. Round 6's implicit occupancy-2 target capped VGPRs
// at 64 (observed VGPR_Count=56), so the compiler REMATERIALIZED the 64-VGPR
// bw[8][2] weight fragments from memory EVERY STEP: 8 MB/XCD/step of L2+L3
// traffic (invisible in FETCH_SIZE since whhT is L3-resident) = the round-6
// bottleneck. Grid is 256 blocks = 1/CU, so the reserved second block slot
// never existed; the extra registers are free.
// ---------------------------------------------------------------------------
template <typename T>
__global__ __launch_bounds__(1024, 4) void lstm_rec(
        const bf16* __restrict__ whhT,
        const T* __restrict__ xh,         // [8 g][8192 sn][1024 h]
        const float* __restrict__ mask,
        unsigned* __restrict__ hstate,    // [4 slot][8 xcd][8 n][1024] bf16
        unsigned* __restrict__ flags,     // [8 xcd][32 local] u32, step counter
        float* __restrict__ out) {
    __shared__ float part[16 * 1024];     // [16 w][8 n][4 gate][32 col] f32 = 64 KB

    const int bi    = blockIdx.x;
    const int xcd   = bi & 7;
    const int local = bi >> 3;            // 0..31
    const int dir   = xcd & 1;
    const int ng    = xcd >> 1;           // batch group: n = ng*8 + un
    const int col0  = local * 32;
    const int tid   = threadIdx.x;
    const int w     = tid >> 6;           // wave 0..15 -> K-slice w*64
    const int lane  = tid & 63;
    const int r16   = lane & 15;
    const int q     = lane >> 4;
    const int kbase = w * 64;

    // ---- pin Whh^T: [8 colTile c][2 it] frags = 64 VGPR (now actually pinned)
    //      c: gate = c>>1, colsub = (c&1)*16; K: kbase + it*32 + q*8 ----
    bf16x8 bw[8][2];
#pragma unroll
    for (int c = 0; c < 8; c++) {
        const size_t rowoff =
            ((size_t)((dir * 4 + (c >> 1)) * 1024 + col0 + (c & 1) * 16 + r16)) * 1024
            + kbase + q * 8;
#pragma unroll
        for (int it = 0; it < 2; it++)
            bw[c][it] = *(const bf16x8*)(whhT + rowoff + it * 32);
    }

    // ---- update-thread state: tid<256 owns (un = tid>>5, uc = tid&31) ----
    const int un = tid >> 5;
    const int uc = tid & 31;
    float creg = 0.f, hreg = 0.f;

    const unsigned* fp = flags + xcd * 32 + (lane & 31);
    const f32x4 vzero = {0.f, 0.f, 0.f, 0.f};

    for (int t = 0; t < S_LEN; ++t) {
        const int s_idx = dir ? (S_LEN - 1 - t) : t;

        // ---- issue xh + mask loads first (HBM latency hides under flag wait) ----
        float xf = 0.f, xi = 0.f, xo = 0.f, xg = 0.f, mt = 0.f;
        if (tid < 256) {
            const size_t xb = ((size_t)(dir * 4) * GSTRIDE)
                            + ((size_t)(s_idx * 32 + ng * 8 + un)) * 1024 + col0 + uc;
            xf = (float)xh[xb];
            xi = (float)xh[xb + GSTRIDE];
            xo = (float)xh[xb + 2 * GSTRIDE];
            xg = (float)xh[xb + 3 * GSTRIDE];
            mt = mask[(ng * 8 + un) * S_LEN + s_idx];
        }

        // ---- flag wait: one 128 B line per XCD ----
        {
            int fg = 0;
            while (true) {
                const unsigned fl = __hip_atomic_load(fp,
                    __ATOMIC_RELAXED, __HIP_MEMORY_SCOPE_AGENT);
                if (__all((int)fl >= t) || ++fg > (1 << 20)) break;
            }
        }

        // ---- bulk h read, once: lanes r16<8 read 32 B of row n=r16 ----
        u64 hq[4];
        hq[0] = 0; hq[1] = 0; hq[2] = 0; hq[3] = 0;
        const u64* Hq = (const u64*)hstate
            + ((size_t)(((t & 3) * 8 + xcd) * 8 + r16)) * 256
            + (kbase >> 2) + q * 2;
        if (r16 < 8) {
            // u64 offsets 0,1 = k [kbase+q*8, +8); offsets 8,9 = k +32 elems
            hq[0] = __hip_atomic_load(Hq,     __ATOMIC_RELAXED, __HIP_MEMORY_SCOPE_AGENT);
            hq[1] = __hip_atomic_load(Hq + 1, __ATOMIC_RELAXED, __HIP_MEMORY_SCOPE_AGENT);
            hq[2] = __hip_atomic_load(Hq + 8, __ATOMIC_RELAXED, __HIP_MEMORY_SCOPE_AGENT);
            hq[3] = __hip_atomic_load(Hq + 9, __ATOMIC_RELAXED, __HIP_MEMORY_SCOPE_AGENT);
            // sentinel backstop (cold: flag gate makes staleness ~impossible)
            int guard = 0;
            while (true) {
                const bool st = is_stale(hq[0]) | is_stale(hq[1])
                              | is_stale(hq[2]) | is_stale(hq[3]);
                if (!st || ++guard > 8192) break;
                if (is_stale(hq[0]))
                    hq[0] = __hip_atomic_load(Hq,     __ATOMIC_RELAXED, __HIP_MEMORY_SCOPE_AGENT);
                if (is_stale(hq[1]))
                    hq[1] = __hip_atomic_load(Hq + 1, __ATOMIC_RELAXED, __HIP_MEMORY_SCOPE_AGENT);
                if (is_stale(hq[2]))
                    hq[2] = __hip_atomic_load(Hq + 8, __ATOMIC_RELAXED, __HIP_MEMORY_SCOPE_AGENT);
                if (is_stale(hq[3]))
                    hq[3] = __hip_atomic_load(Hq + 9, __ATOMIC_RELAXED, __HIP_MEMORY_SCOPE_AGENT);
            }
        }

        // ---- h(t) @ Whh^T: 16 MFMAs, partials -> LDS as we go ----
        union { u64 qv[2]; bf16x8 v; } av0, av1;
        av0.qv[0] = hq[0]; av0.qv[1] = hq[1];   // k = kbase + q*8 .. +7
        av1.qv[0] = hq[2]; av1.qv[1] = hq[3];   // k = kbase + 32 + q*8 .. +7
#pragma unroll
        for (int c = 0; c < 8; c++) {
            f32x4 a = vzero;
            a = __builtin_amdgcn_mfma_f32_16x16x32_bf16(av0.v, bw[c][0], a, 0, 0, 0);
            a = __builtin_amdgcn_mfma_f32_16x16x32_bf16(av1.v, bw[c][1], a, 0, 0, 0);
            if (lane < 32) {
#pragma unroll
                for (int j = 0; j < 4; j++)
                    part[w * 1024 + (q * 4 + j) * 128 + (c >> 1) * 32 + (c & 1) * 16 + r16]
                        = a[j];
            }
        }
        __syncthreads();

        // ---- cell update ----
        if (tid < 256) {
            // reset slot t+2 to sentinel (lockstep: nobody reads slot t+2 now)
            if ((uc & 3) == 0) {
                u64* rdst = (u64*)hstate
                    + ((size_t)((((t + 2) & 3) * 8 + xcd) * 8 + un)) * 256
                    + ((col0 + uc) >> 2);
                __hip_atomic_store(rdst, SENT64, __ATOMIC_RELAXED, __HIP_MEMORY_SCOPE_AGENT);
            }
            float pf = xf, pi = xi, po = xo, pg = xg;
#pragma unroll
            for (int ww = 0; ww < 16; ww++) {
                const float* p = part + ww * 1024 + un * 128;
                pf += p[uc];
                pi += p[32 + uc];
                po += p[64 + uc];
                pg += p[96 + uc];
            }
            const float f  = fast_sig(pf);
            const float i  = fast_sig(pi);
            const float o  = fast_sig(po);
            const float ct = fast_tanh(pg);
            creg = f * creg + i * ct;                 // c updated regardless of mask
            const float hnew = o * fast_tanh(creg);
            const float hcar = (mt == 0.f) ? hreg : hnew;
            hreg = hcar;
            // publish h(t+1): pack 4 cols -> u64, lanes uc&3==0 store
            union { bf16 b; unsigned short u; } cv;
            cv.b = (bf16)hcar;
            const unsigned mine  = cv.u;
            const unsigned other = (unsigned)__shfl_xor((int)mine, 1);
            const unsigned pair  = mine | (other << 16);
            const unsigned pair2 = (unsigned)__shfl_xor((int)pair, 2);
            if ((uc & 3) == 0) {
                u64* dst = (u64*)hstate
                    + ((size_t)((((t + 1) & 3) * 8 + xcd) * 8 + un)) * 256
                    + ((col0 + uc) >> 2);
                __hip_atomic_store(dst, (u64)pair | ((u64)pair2 << 32),
                                   __ATOMIC_RELAXED, __HIP_MEMORY_SCOPE_AGENT);
            }
            out[((size_t)((ng * 8 + un) * S_LEN + s_idx)) * 2048 + dir * 1024 + col0 + uc]
                = hcar * mt;
            if (t == S_LEN - 1)
                out[(size_t)NBATCH * S_LEN * 2048 + (ng * 8 + un) * 2048 + dir * 1024 + col0 + uc]
                    = hcar;
        }
        __syncthreads();   // part[] consumed; per-wave vmcnt(0) drains publishes

        // ---- signal: this block's h(t+1) is L2-visible ----
        if (tid == 0)
            __hip_atomic_store(flags + xcd * 32 + local, (unsigned)(t + 1),
                               __ATOMIC_RELAXED, __HIP_MEMORY_SCOPE_AGENT);
    }
}

// ---------------------------------------------------------------------------
// Fallback: round-2 verified persistent kernel (51 MB workspace, 2291 µs).
// ---------------------------------------------------------------------------
__global__ __launch_bounds__(1024) void lstm_persistent(
        const bf16* __restrict__ xT,
        const bf16* __restrict__ wihT,
        const bf16* __restrict__ whhT,
        const float* __restrict__ mask,
        const float* __restrict__ bias,
        unsigned* __restrict__ hbuf,    // [4 slot][2 dir][32 n][512] u32
        float* __restrict__ out) {
    __shared__ float part[16 * 1024];

    const int bi   = blockIdx.x;
    const int dir  = bi & 1;
    const int col0 = ((bi >> 1) & 127) << 3;
    const int tid  = threadIdx.x;
    const int w    = tid >> 6;
    const int lane = tid & 63;
    const int r    = lane & 15;
    const int q    = lane >> 4;
    const int kbase = w * 64 + q * 8;

    bf16x8 bx[2][2], bh[2][2];
#pragma unroll
    for (int gp = 0; gp < 2; gp++) {
        const int gate = gp * 2 + (r >> 3);
        const size_t rowoff = ((size_t)((dir * 4 + gate) * 1024 + col0 + (r & 7))) * 1024 + kbase;
#pragma unroll
        for (int it = 0; it < 2; it++) {
            bx[gp][it] = *(const bf16x8*)(wihT + rowoff + it * 32);
            bh[gp][it] = *(const bf16x8*)(whhT + rowoff + it * 32);
        }
    }

    const int un = tid >> 3;
    const int uc = tid & 7;
    float creg = 0.f, hreg = 0.f;
    float b0 = 0.f, b1 = 0.f, b2 = 0.f, b3 = 0.f;
    if (tid < 256) {
        const int gb = (dir * 4) * 1024 + col0 + uc;
        b0 = bias[gb];
        b1 = bias[gb + 1024];
        b2 = bias[gb + 2048];
        b3 = bias[gb + 3072];
    }
    const int rx = (un & 7) * 4;

    const f32x4 vzero = {0.f, 0.f, 0.f, 0.f};
    f32x4 accA[2][2], accB[2][2];
#pragma unroll
    for (int mh = 0; mh < 2; mh++) { accB[mh][0] = vzero; accB[mh][1] = vzero; }

    {
        const int s_id = dir ? (S_LEN - 1) : 0;
        const bf16* Ax = xT + (size_t)s_id * NBATCH * HDIM + kbase;
#pragma unroll
        for (int mh = 0; mh < 2; mh++) {
            accA[mh][0] = vzero; accA[mh][1] = vzero;
#pragma unroll
            for (int it = 0; it < 2; it++) {
                bf16x8 a = *(const bf16x8*)(Ax + (size_t)(mh * 16 + r) * HDIM + it * 32);
                accA[mh][0] = __builtin_amdgcn_mfma_f32_16x16x32_bf16(a, bx[0][it], accA[mh][0], 0, 0, 0);
                accA[mh][1] = __builtin_amdgcn_mfma_f32_16x16x32_bf16(a, bx[1][it], accA[mh][1], 0, 0, 0);
            }
        }
    }

    for (int t = 0; t < S_LEN; ++t) {
        const int s_idx = dir ? (S_LEN - 1 - t) : t;
        float mt = 0.f;
        if (tid < 256) mt = mask[un * S_LEN + s_idx];

        const u64* Hp = (const u64*)hbuf
                      + ((size_t)((t & 3) * 2 + dir) * NBATCH) * 256 + (kbase >> 2);
        u64 hv[2][2][2];
#pragma unroll
        for (int mh = 0; mh < 2; mh++)
#pragma unroll
            for (int it = 0; it < 2; it++)
#pragma unroll
                for (int j = 0; j < 2; j++)
                    hv[mh][it][j] = __hip_atomic_load(
                        Hp + (size_t)(mh * 16 + r) * 256 + it * 8 + j,
                        __ATOMIC_RELAXED, __HIP_MEMORY_SCOPE_AGENT);

        if (t + 1 < S_LEN) {
            const int s_id = dir ? (S_LEN - 2 - t) : (t + 1);
            const bf16* Ax = xT + (size_t)s_id * NBATCH * HDIM + kbase;
#pragma unroll
            for (int mh = 0; mh < 2; mh++) {
                accB[mh][0] = vzero; accB[mh][1] = vzero;
#pragma unroll
                for (int it = 0; it < 2; it++) {
                    bf16x8 a = *(const bf16x8*)(Ax + (size_t)(mh * 16 + r) * HDIM + it * 32);
                    accB[mh][0] = __builtin_amdgcn_mfma_f32_16x16x32_bf16(a, bx[0][it], accB[mh][0], 0, 0, 0);
                    accB[mh][1] = __builtin_amdgcn_mfma_f32_16x16x32_bf16(a, bx[1][it], accB[mh][1], 0, 0, 0);
                }
            }
        }

        {
            int guard = 0;
            while (true) {
                bool stale = false;
#pragma unroll
                for (int mh = 0; mh < 2; mh++)
#pragma unroll
                    for (int it = 0; it < 2; it++)
#pragma unroll
                        for (int j = 0; j < 2; j++)
                            stale |= is_stale(hv[mh][it][j]);
                if (!stale || ++guard > 8192) break;
#pragma unroll
                for (int mh = 0; mh < 2; mh++)
#pragma unroll
                    for (int it = 0; it < 2; it++)
#pragma unroll
                        for (int j = 0; j < 2; j++)
                            if (is_stale(hv[mh][it][j]))
                                hv[mh][it][j] = __hip_atomic_load(
                                    Hp + (size_t)(mh * 16 + r) * 256 + it * 8 + j,
                                    __ATOMIC_RELAXED, __HIP_MEMORY_SCOPE_AGENT);
            }
        }

#pragma unroll
        for (int mh = 0; mh < 2; mh++)
#pragma unroll
            for (int it = 0; it < 2; it++) {
                union { u64 qv[2]; bf16x8 v; } av;
                av.qv[0] = hv[mh][it][0];
                av.qv[1] = hv[mh][it][1];
                accA[mh][0] = __builtin_amdgcn_mfma_f32_16x16x32_bf16(av.v, bh[0][it], accA[mh][0], 0, 0, 0);
                accA[mh][1] = __builtin_amdgcn_mfma_f32_16x16x32_bf16(av.v, bh[1][it], accA[mh][1], 0, 0, 0);
            }

        {
            float* slab = part + w * 1024;
#pragma unroll
            for (int mh = 0; mh < 2; mh++)
#pragma unroll
                for (int gp = 0; gp < 2; gp++)
#pragma unroll
                    for (int rr = 0; rr < 4; rr++) {
                        const int row = mh * 16 + q * 4 + rr;
                        const int pc = (gp * 16 + r) ^ ((row & 7) * 4);
                        slab[row * 32 + pc] = accA[mh][gp][rr];
                    }
        }
#pragma unroll
        for (int mh = 0; mh < 2; mh++) { accA[mh][0] = accB[mh][0]; accA[mh][1] = accB[mh][1]; }
        __syncthreads();

        if (tid < 256) {
            if ((uc & 3) == 0) {
                u64* rdst = (u64*)hbuf
                    + ((size_t)(((t + 2) & 3) * 2 + dir) * NBATCH + un) * 256
                    + ((col0 + uc) >> 2);
                __hip_atomic_store(rdst, SENT64, __ATOMIC_RELAXED, __HIP_MEMORY_SCOPE_AGENT);
            }
            float pf = b0, pi = b1, po = b2, pg = b3;
            const int rowbase = un * 32;
#pragma unroll
            for (int ww = 0; ww < 16; ww++) {
                const float* rowp = part + ww * 1024 + rowbase;
                pf += rowp[(0  + uc) ^ rx];
                pi += rowp[(8  + uc) ^ rx];
                po += rowp[(16 + uc) ^ rx];
                pg += rowp[(24 + uc) ^ rx];
            }
            const float f  = fast_sig(pf);
            const float i  = fast_sig(pi);
            const float o  = fast_sig(po);
            const float ct = fast_tanh(pg);
            creg = f * creg + i * ct;
            const float hnew = o * fast_tanh(creg);
            const float hcar = (mt == 0.f) ? hreg : hnew;
            hreg = hcar;
            union { bf16 b; unsigned short u; } cv;
            cv.b = (bf16)hcar;
            const unsigned mine  = cv.u;
            const unsigned other = (unsigned)__shfl_xor((int)mine, 1);
            const unsigned pair  = mine | (other << 16);
            const unsigned pair2 = (unsigned)__shfl_xor((int)pair, 2);
            if ((uc & 3) == 0) {
                u64* dst = (u64*)hbuf
                    + ((size_t)(((t + 1) & 3) * 2 + dir) * NBATCH + un) * 256
                    + ((col0 + uc) >> 2);
                __hip_atomic_store(dst, (u64)pair | ((u64)pair2 << 32),
                                   __ATOMIC_RELAXED, __HIP_MEMORY_SCOPE_AGENT);
            }
            out[((size_t)(un * S_LEN + s_idx)) * 2048 + dir * 1024 + col0 + uc] = hcar * mt;
            if (t == S_LEN - 1)
                out[(size_t)NBATCH * S_LEN * 2048 + un * 2048 + dir * 1024 + col0 + uc] = hcar;
        }
        __syncthreads();
    }
}

// ---------------------------------------------------------------------------
// Workspace layouts (adaptive on ws_size):
//   common: [0,16MB) xT | [16,32MB) wihT | [32,48MB) whhT
//   A (ws >= 319292416): xh f32 at 48MB, hstate at 318767104, flags +524288
//   B (ws >= 185074688): xh bf16 at 48MB, hstate at 184549376, flags +524288
//   C (else):            round-2 hbuf at 48MB (51 MB total, verified)
// ---------------------------------------------------------------------------
extern "C" void kernel_launch(void* const* d_in, const int* in_sizes, int n_in,
                              void* d_out, int out_size, void* d_ws, size_t ws_size,
                              hipStream_t stream) {
    const float* x    = (const float*)d_in[0];
    const float* mask = (const float*)d_in[1];
    const float* wih  = (const float*)d_in[2];
    const float* whh  = (const float*)d_in[3];
    const float* bias = (const float*)d_in[4];
    float* out = (float*)d_out;

    char* ws = (char*)d_ws;
    bf16* xT   = (bf16*)(ws);
    bf16* wihT = (bf16*)(ws + 16777216);
    bf16* whhT = (bf16*)(ws + 33554432);

    convert_x<<<NBATCH * S_LEN, 256, 0, stream>>>(x, xT);
    dim3 tb(32, 8);
    convert_transpose_1024<<<dim3(32, 32, 8), tb, 0, stream>>>(wih, wihT);
    convert_transpose_1024<<<dim3(32, 32, 8), tb, 0, stream>>>(whh, whhT);

    if (ws_size >= 319292416ull) {
        // Path A: f32 xh
        float*    xh     = (float*)(ws + 50331648);
        unsigned* hstate = (unsigned*)(ws + 318767104);
        unsigned* flags  = (unsigned*)(ws + 318767104 + 524288);
        hipMemsetAsync((char*)hstate, 0x00, 131072, stream);
        hipMemsetAsync((char*)hstate + 131072, 0x7F, 393216, stream);
        hipMemsetAsync((char*)flags, 0x00, 1024, stream);
        xh_gemm<float><<<dim3(64, 8, 8), 256, 0, stream>>>(xT, wihT, bias, xh);
        lstm_rec<float><<<256, 1024, 0, stream>>>(whhT, xh, mask, hstate, flags, out);
    } else if (ws_size >= 185074688ull) {
        // Path B: bf16 xh
        bf16*     xh     = (bf16*)(ws + 50331648);
        unsigned* hstate = (unsigned*)(ws + 184549376);
        unsigned* flags  = (unsigned*)(ws + 184549376 + 524288);
        hipMemsetAsync((char*)hstate, 0x00, 131072, stream);
        hipMemsetAsync((char*)hstate + 131072, 0x7F, 393216, stream);
        hipMemsetAsync((char*)flags, 0x00, 1024, stream);
        xh_gemm<bf16><<<dim3(64, 8, 8), 256, 0, stream>>>(xT, wihT, bias, xh);
        lstm_rec<bf16><<<256, 1024, 0, stream>>>(whhT, xh, mask, hstate, flags, out);
    } else {
        // Path C: verified round-2 fused persistent kernel
        unsigned* hbuf = (unsigned*)(ws + 50331648);
        hipMemsetAsync((char*)hbuf, 0x00, 131072, stream);
        hipMemsetAsync((char*)hbuf + 131072, 0x7F, 393216, stream);
        lstm_persistent<<<NBLK, 1024, 0, stream>>>(xT, wihT, whhT, mask, bias,
                                                   hbuf, out);
    }
}